// Round 13
// baseline (1284.946 us; speedup 1.0000x reference)
//
#include <hip/hip_runtime.h>
#include <hip/hip_bf16.h>
#include <math.h>

// ---------------------------------------------------------------------------
// TCCL model forward. Round 12:
//  - finalize folded into conv kernels (last-block-reduces: transposed
//    partials + threadfence + agent-scope atomic counter; counter self-resets
//    -> deterministic + graph-replay idempotent). 5 launches removed.
//  - final3 folded into simdot_nce (same pattern). 1 launch removed.
//  - wpack kernel removed: stage-1 fragment read per-lane from w1 directly;
//    other packs built by blocks 0..299 of the stage-1 stats kernel.
//  - stage-1 WT 8->16 (grid 8192->4096).
//  - 9 dispatches total (memset + 8 kernels), was 15.
// ---------------------------------------------------------------------------

#define BSZ2 512
#define NTHR 256
#define PSTRIDE 4096      // max nblk (stage1 = 4096)

typedef __attribute__((ext_vector_type(8))) short bf16x8;
typedef __attribute__((ext_vector_type(4))) float f32x4;

__device__ __forceinline__ unsigned short f2bf(float f) {
    unsigned u = __float_as_uint(f);
    u = (u + 0x7FFFu + ((u >> 16) & 1u)) >> 16;
    return (unsigned short)u;
}
__device__ __forceinline__ float bflo(unsigned u) { return __uint_as_float(u << 16); }
__device__ __forceinline__ float bfhi(unsigned u) { return __uint_as_float(u & 0xFFFF0000u); }

// ---------------- last-block finalize (device-side) --------------------------
// pT rows: co*2+slot (slot 0=sum,1=sumsq), entries indexed by blockIdx
// (batch-major: first nblk/2 blocks = half 0).
template<int COUT>
__device__ void lb_finalize(float* __restrict__ pT, unsigned* __restrict__ counter,
                            float invN, const float* __restrict__ g,
                            const float* __restrict__ be,
                            float* __restrict__ scale, float* __restrict__ shift)
{
    const int tid = threadIdx.x;
    const int nblk = gridDim.x * gridDim.y;
    __threadfence();
    __syncthreads();
    __shared__ unsigned done_s;
    if (tid == 0)
        done_s = __hip_atomic_fetch_add(counter, 1u, __ATOMIC_ACQ_REL, __HIP_MEMORY_SCOPE_AGENT);
    __syncthreads();
    if (done_s != (unsigned)(nblk - 1)) return;
    __threadfence();

    constexpr int GROUPS = COUT * 4;          // (co, slot, half)
    constexpr int SEG = 256 / GROUPS;         // threads per group (pow2 >= 1)
    __shared__ float gsum[256];
    const int nh = nblk >> 1;
    float s = 0.f;
    {
        const int grp = tid / SEG;
        const int seg = tid % SEG;
        const int half = grp & 1;
        const int slot = (grp >> 1) & 1;
        const int co = grp >> 2;
        const int cnt = nh / SEG;
        const float* p = pT + (size_t)(co * 2 + slot) * PSTRIDE + half * nh + seg * cnt;
        const float4* p4 = (const float4*)p;
        float4 av = {0.f, 0.f, 0.f, 0.f};
        for (int i = 0; i < cnt / 4; ++i) {
            const float4 v = p4[i];
            av.x += v.x; av.y += v.y; av.z += v.z; av.w += v.w;
        }
        s = av.x + av.y + av.z + av.w;
    }
    gsum[tid] = s;
    __syncthreads();
    if (tid < COUT * 2) {                     // (co, half)
        const int half = tid & 1;
        const int co = tid >> 1;
        float sv = 0.f, qv = 0.f;
#pragma unroll
        for (int e = 0; e < SEG; ++e) {
            sv += gsum[(co * 4 + 0 + half) * SEG + e];
            qv += gsum[(co * 4 + 2 + half) * SEG + e];
        }
        const float m = sv * invN;
        const float var = qv * invN - m * m;
        const float inv = rsqrtf(var + 1e-5f);
        const float sc = g[co] * inv;
        scale[half * COUT + co] = sc;
        shift[half * COUT + co] = be[co] - sc * m;
    }
    __threadfence();
    if (tid == 0)
        __hip_atomic_store(counter, 0u, __ATOMIC_RELEASE, __HIP_MEMORY_SCOPE_AGENT);
}

// ---------------- weight prepack helper --------------------------------------
template<int CIN, int KK, int DT, int NP, int S, int CT>
__device__ __forceinline__ void pack_one(int idx, const float* __restrict__ wgt,
                                         unsigned short* __restrict__ wp)
{
    const int j = idx & 7;
    const int l = (idx >> 3) & 63;
    int rest = idx >> 9;
    const int ct = rest % CT; rest /= CT;
    const int s = rest % S;
    const int p = rest / S;
    const int co = ct * 16 + (l & 15);
    const int k = (l >> 4) * 8 + j;
    int ci, t;
    if (DT == 2) { ci = k & (CIN - 1); t = p * 2 + (k >> 4); }
    else         { ci = s * 32 + k;    t = p; }
    float v = (t < KK) ? wgt[((long long)co * CIN + ci) * KK + t] : 0.f;
    wp[idx] = f2bf(v);
}

// ---------------- stage 1 MFMA conv (Cin=1, K=17 padded to 32) ---------------
// D[w][co], co = lane&15, w = kq*4+e. MODE 0 = stats (+pack duty, +finalize);
// MODE 1 = BN+ReLU+maxpool4 -> bf16 [b][wp][16]
template<int WT, int MODE>
__global__ __launch_bounds__(256)
void conv1_mfma(const float* __restrict__ x1, const float* __restrict__ x2,
                const float* __restrict__ w1, const float* __restrict__ bias,
                const float* __restrict__ g, const float* __restrict__ be,
                float* __restrict__ scale, float* __restrict__ shift,
                unsigned short* __restrict__ out,
                float* __restrict__ pT, unsigned* __restrict__ counter, float invN,
                const float* __restrict__ w2, const float* __restrict__ w3,
                const float* __restrict__ tw1, const float* __restrict__ tw2,
                unsigned short* __restrict__ wp2, unsigned short* __restrict__ wp3,
                unsigned short* __restrict__ wpt1, unsigned short* __restrict__ wpt2)
{
    constexpr int W = 8192;
    constexpr int CHUNK = 4 * WT * 16;
    __shared__ float xs[CHUNK + 32];
    __shared__ float sred[4][16];
    __shared__ float ssred[4][16];

    const int tid = threadIdx.x;

    // pack duty (stats pass only; consumed 2 kernels later)
    if (MODE == 0 && blockIdx.x < 300) {
        const int idx = blockIdx.x * 256 + tid;   // < 76800
        const int n2 = 9216, n3 = 34816, nt1 = 20480;
        if (idx < n2) pack_one<16, 17, 2, 9, 1, 2>(idx, w2, wp2);
        else if (idx < n2 + n3) pack_one<32, 17, 1, 17, 1, 4>(idx - n2, w3, wp3);
        else if (idx < n2 + n3 + nt1) pack_one<64, 5, 1, 5, 2, 4>(idx - n2 - n3, tw1, wpt1);
        else pack_one<64, 3, 1, 3, 2, 4>(idx - n2 - n3 - nt1, tw2, wpt2);
    }

    const int ntile = W / CHUNK;
    const int b = blockIdx.x / ntile;
    const int w0 = (blockIdx.x % ntile) * CHUNK;
    const float* xrow = (b < 256) ? x1 + (long long)b * W : x2 + (long long)(b - 256) * W;

    for (int i = tid; i < CHUNK + 32; i += 256) {
        const int gw = w0 - 8 + i;
        xs[i] = (gw >= 0 && gw < W) ? xrow[gw] : 0.f;
    }
    __syncthreads();

    const int lane = tid & 63, wave = tid >> 6;
    const int n = lane & 15, kq = lane >> 4;
    // weight fragment direct from w1 (1KB table, L1): co=n, k=kq*8+j
    bf16x8 a;
#pragma unroll
    for (int j = 0; j < 8; ++j) {
        const int k = kq * 8 + j;
        const float wv = (k < 17) ? w1[n * 17 + k] : 0.f;
        __hip_bfloat16 h = __float2bfloat16(wv);
        a[j] = *reinterpret_cast<const short*>(&h);
    }

    f32x4 acc[WT];
#pragma unroll
    for (int wt = 0; wt < WT; ++wt) { acc[wt][0]=0.f; acc[wt][1]=0.f; acc[wt][2]=0.f; acc[wt][3]=0.f; }

    const int base0 = wave * WT * 16 + n + kq * 8;
#pragma unroll
    for (int wt = 0; wt < WT; ++wt) {
        bf16x8 bv;
#pragma unroll
        for (int j = 0; j < 8; ++j) {
            __hip_bfloat16 h = __float2bfloat16(xs[base0 + wt * 16 + j]);
            bv[j] = *reinterpret_cast<const short*>(&h);
        }
        acc[wt] = __builtin_amdgcn_mfma_f32_16x16x32_bf16(bv, a, acc[wt], 0, 0, 0);  // D[w][co]
    }

    if (MODE == 0) {
        const float bi = bias[n];
        float s_ = 0.f, ss_ = 0.f;
#pragma unroll
        for (int wt = 0; wt < WT; ++wt)
#pragma unroll
            for (int e = 0; e < 4; ++e) {
                const float y = acc[wt][e] + bi;
                s_ += y; ss_ += y * y;
            }
        s_  += __shfl_xor(s_, 16, 64);  s_  += __shfl_xor(s_, 32, 64);
        ss_ += __shfl_xor(ss_, 16, 64); ss_ += __shfl_xor(ss_, 32, 64);
        if (lane < 16) { sred[wave][n] = s_; ssred[wave][n] = ss_; }
        __syncthreads();
        if (tid < 16) {
            float sumv = 0.f, sumsq = 0.f;
#pragma unroll
            for (int wv = 0; wv < 4; ++wv) { sumv += sred[wv][tid]; sumsq += ssred[wv][tid]; }
            pT[(size_t)(tid * 2 + 0) * PSTRIDE + blockIdx.x] = sumv;
            pT[(size_t)(tid * 2 + 1) * PSTRIDE + blockIdx.x] = sumsq;
        }
        lb_finalize<16>(pT, counter, invN, g, be, scale, shift);
    } else {
        const int half = b >> 8;
        const float bi = bias[n];
        const float scv = scale[half * 16 + n];
        const float shv = shift[half * 16 + n];
#pragma unroll
        for (int wt = 0; wt < WT; ++wt) {
            float v[4];
#pragma unroll
            for (int e = 0; e < 4; ++e) v[e] = fmaf(scv, acc[wt][e] + bi, shv);
            const float mx = fmaxf(fmaxf(fmaxf(v[0], v[1]), fmaxf(v[2], v[3])), 0.f);
            const int wp = (w0 >> 2) + wave * WT * 4 + wt * 4 + kq;
            out[((long long)b * 2048 + wp) * 16 + n] = f2bf(mx);
        }
    }
}

// ---------------- MFMA conv, generalized (swapped operands, self-finalize) ---
// D[w][co]: co = ct*16 + (lane&15), w = w0 + wave*ST*16 + st*16 + kq*4 + e
// SRCM: 0 = src bf16 as-is; 1 = (max,min) pair + prev BN select + relu;
//       2 = raw y + prev BN + relu
// OUTM: 0 = store raw y; 1 = store pooled (max,min) of raw y
template<int CIN, int COUT, int KK, int PAD, int DT, int NP, int S, int CT, int ST,
         int SRCM, int OUTM>
__global__ __launch_bounds__(256)
void conv_mfma2(const unsigned short* __restrict__ xA, const unsigned short* __restrict__ xB,
                const float* __restrict__ pscale, const float* __restrict__ pshift,
                const unsigned short* __restrict__ wpack, const float* __restrict__ bias,
                unsigned short* __restrict__ outA, unsigned short* __restrict__ outB,
                const float* __restrict__ g, const float* __restrict__ be,
                float* __restrict__ oscale, float* __restrict__ oshift,
                float* __restrict__ pT, unsigned* __restrict__ counter, float invN, int W)
{
    constexpr int CHUNK = 4 * ST * 16;
    constexpr int ROWB = CIN * 2 + 16;
    constexpr int ROWS = CHUNK + KK + (DT - 1) + 1;
    constexpr int DPR = CIN / 2;
    __shared__ __align__(16) unsigned char lx[ROWS * ROWB];
    __shared__ float sred[4][CT][16];
    __shared__ float ssred[4][CT][16];
    __shared__ float scb[(SRCM > 0) ? CIN : 1];
    __shared__ float shb[(SRCM > 0) ? CIN : 1];

    const int tid = threadIdx.x;
    const int ntile = W / CHUNK;
    const int b = blockIdx.x / ntile;
    const int tile = blockIdx.x % ntile;
    const int w0 = tile * CHUNK;

    if (SRCM > 0) {
        if (tid < CIN) {
            scb[tid] = pscale[(b >> 8) * CIN + tid];
            shb[tid] = pshift[(b >> 8) * CIN + tid];
        }
        __syncthreads();
    }

    for (int d = tid; d < ROWS * DPR; d += 256) {
        const int row = d / DPR;
        const int col = d % DPR;
        const int gw = w0 - PAD + row;
        unsigned v = 0;
        if (gw >= 0 && gw < W) {
            const long long src = ((long long)b * W + gw) * CIN + col * 2;
            if (SRCM == 0) {
                v = *(const unsigned*)(xA + src);
            } else {
                const unsigned va = *(const unsigned*)(xA + src);
                const float sc0 = scb[col * 2], sh0 = shb[col * 2];
                const float sc1 = scb[col * 2 + 1], sh1 = shb[col * 2 + 1];
                float f0, f1;
                if (SRCM == 1) {
                    const unsigned vb = *(const unsigned*)(xB + src);
                    f0 = fmaxf(fmaf(sc0, (sc0 > 0.f) ? bflo(va) : bflo(vb), sh0), 0.f);
                    f1 = fmaxf(fmaf(sc1, (sc1 > 0.f) ? bfhi(va) : bfhi(vb), sh1), 0.f);
                } else {
                    f0 = fmaxf(fmaf(sc0, bflo(va), sh0), 0.f);
                    f1 = fmaxf(fmaf(sc1, bfhi(va), sh1), 0.f);
                }
                v = (unsigned)f2bf(f0) | ((unsigned)f2bf(f1) << 16);
            }
        }
        *(unsigned*)(lx + row * ROWB + col * 4) = v;
    }
    __syncthreads();

    const int lane = tid & 63, wave = tid >> 6;
    const int n = lane & 15, kq = lane >> 4;
    int rowbase, cbyte;
    if (DT == 2) { rowbase = wave * ST * 16 + n + (kq >> 1); cbyte = (kq & 1) * 16; }
    else         { rowbase = wave * ST * 16 + n;             cbyte = kq * 16; }

    f32x4 acc[ST][CT];
#pragma unroll
    for (int st = 0; st < ST; ++st)
#pragma unroll
        for (int ct = 0; ct < CT; ++ct) { acc[st][ct][0]=0.f; acc[st][ct][1]=0.f; acc[st][ct][2]=0.f; acc[st][ct][3]=0.f; }

#pragma unroll
    for (int p = 0; p < NP; ++p) {
#pragma unroll
        for (int s = 0; s < S; ++s) {
            bf16x8 a[CT];
#pragma unroll
            for (int ct = 0; ct < CT; ++ct)
                a[ct] = *(const bf16x8*)(wpack + (((long long)(p * S + s) * CT + ct) * 64 + lane) * 8);
#pragma unroll
            for (int st = 0; st < ST; ++st) {
                const int r = rowbase + st * 16 + p * DT;
                const bf16x8 bf = *(const bf16x8*)(lx + r * ROWB + cbyte + s * 64);
#pragma unroll
                for (int ct = 0; ct < CT; ++ct)
                    acc[st][ct] = __builtin_amdgcn_mfma_f32_16x16x32_bf16(bf, a[ct], acc[st][ct], 0, 0, 0);
            }
        }
    }

    float s_[CT], ss_[CT];
#pragma unroll
    for (int ct = 0; ct < CT; ++ct) { s_[ct] = 0.f; ss_[ct] = 0.f; }

#pragma unroll
    for (int st = 0; st < ST; ++st) {
        const int wbase = w0 + wave * ST * 16 + st * 16 + kq * 4;
#pragma unroll
        for (int ct = 0; ct < CT; ++ct) {
            const float bi = bias[ct * 16 + n];
            float v[4];
#pragma unroll
            for (int e = 0; e < 4; ++e) {
                v[e] = acc[st][ct][e] + bi;
                s_[ct] += v[e];
                ss_[ct] += v[e] * v[e];
            }
            if (OUTM == 0) {
#pragma unroll
                for (int e = 0; e < 4; ++e)
                    outA[((long long)b * W + wbase + e) * COUT + ct * 16 + n] = f2bf(v[e]);
            } else {
                const float mx = fmaxf(fmaxf(v[0], v[1]), fmaxf(v[2], v[3]));
                const float mn = fminf(fminf(v[0], v[1]), fminf(v[2], v[3]));
                const long long o = ((long long)b * (W >> 2) + (wbase >> 2)) * COUT + ct * 16 + n;
                outA[o] = f2bf(mx);
                outB[o] = f2bf(mn);
            }
        }
    }
#pragma unroll
    for (int ct = 0; ct < CT; ++ct) {
        s_[ct]  += __shfl_xor(s_[ct], 16, 64);  s_[ct]  += __shfl_xor(s_[ct], 32, 64);
        ss_[ct] += __shfl_xor(ss_[ct], 16, 64); ss_[ct] += __shfl_xor(ss_[ct], 32, 64);
    }
    if (lane < 16) {
#pragma unroll
        for (int ct = 0; ct < CT; ++ct) { sred[wave][ct][n] = s_[ct]; ssred[wave][ct][n] = ss_[ct]; }
    }
    __syncthreads();
    if (tid < COUT) {
        const int ct = tid >> 4, nn = tid & 15;
        float sumv = 0.f, sumsq = 0.f;
#pragma unroll
        for (int wv = 0; wv < 4; ++wv) { sumv += sred[wv][ct][nn]; sumsq += ssred[wv][ct][nn]; }
        pT[(size_t)(tid * 2 + 0) * PSTRIDE + blockIdx.x] = sumv;
        pT[(size_t)(tid * 2 + 1) * PSTRIDE + blockIdx.x] = sumsq;
    }
    lb_finalize<COUT>(pT, counter, invN, g, be, oscale, oshift);
}

// ---------------- fused tail --------------------------------------------------
__global__ void tail_pool_srow(const unsigned short* __restrict__ yT2b,
                               const float* __restrict__ scT2, const float* __restrict__ shT2,
                               const unsigned short* __restrict__ yMax3,
                               const unsigned short* __restrict__ yMin3,
                               const float* __restrict__ scS3, const float* __restrict__ shS3,
                               float* __restrict__ kn, float* __restrict__ ab,
                               float* __restrict__ Sv)
{
    __shared__ float hb[128][64];
    const int tid = threadIdx.x;
    if (blockIdx.x < BSZ2) {
        const int b = blockIdx.x;
        __shared__ float pk[320];
        __shared__ float red2[NTHR];
        const uint2* yd = (const uint2*)(yT2b + (long long)b * 128 * 64);
        for (int i = tid; i < 128 * 16; i += 256) {
            const int w = i >> 4, c4 = (i & 15) * 4;
            const float* scp = scT2 + (b >> 8) * 64 + c4;
            const float* shp = shT2 + (b >> 8) * 64 + c4;
            const uint2 v = yd[i];
            hb[w][c4 + 0] = fmaxf(fmaf(scp[0], bflo(v.x), shp[0]), 0.f);
            hb[w][c4 + 1] = fmaxf(fmaf(scp[1], bfhi(v.x), shp[1]), 0.f);
            hb[w][c4 + 2] = fmaxf(fmaf(scp[2], bflo(v.y), shp[2]), 0.f);
            hb[w][c4 + 3] = fmaxf(fmaf(scp[3], bfhi(v.y), shp[3]), 0.f);
        }
        __syncthreads();
        const int bs[5] = {0, 25, 51, 76, 102};
        const int be5[5] = {26, 52, 77, 103, 128};
        for (int o = tid; o < 320; o += 256) {
            const int cc = o & 63, bin = o >> 6;
            float acc = 0.f;
            for (int w = bs[bin]; w < be5[bin]; ++w) acc += hb[w][cc];
            pk[cc * 5 + bin] = acc / (float)(be5[bin] - bs[bin]);
        }
        __syncthreads();
        float n2p = pk[tid] * pk[tid];
        if (tid < 64) n2p += pk[256 + tid] * pk[256 + tid];
        red2[tid] = n2p;
        __syncthreads();
        for (int off = NTHR / 2; off > 0; off >>= 1) {
            if (tid < off) red2[tid] += red2[tid + off];
            __syncthreads();
        }
        const float nrm = fmaxf(sqrtf(red2[0]), 1e-12f);
        for (int i = tid; i < 320; i += 256) ab[(long long)b * 320 + i] = pk[i] / nrm;
        if (tid < 64) {
            const float* p = pk + tid * 5;
            float m = 0.f;
            for (int t = 0; t < 5; ++t) m += p[t];
            m *= 0.2f;
            float v[5]; float q = 0.f;
            for (int t = 0; t < 5; ++t) { v[t] = p[t] - m; q += v[t] * v[t]; }
            const float n = fmaxf(sqrtf(q), 1e-12f);
            float* o = kn + ((long long)b * 64 + tid) * 5;
            for (int t = 0; t < 5; ++t) o[t] = v[t] / n;
        }
    } else {
        __shared__ float red[4][64];
        __shared__ float mrow[64];
        const int b = blockIdx.x - BSZ2;
        const int c = tid & 63, grp = tid >> 6;
        const uint2* ya = (const uint2*)(yMax3 + (long long)b * 128 * 64);
        const uint2* yb = (const uint2*)(yMin3 + (long long)b * 128 * 64);
        for (int i = tid; i < 128 * 16; i += 256) {
            const int w = i >> 4, c4 = (i & 15) * 4;
            const float* scp = scS3 + (b >> 8) * 64 + c4;
            const float* shp = shS3 + (b >> 8) * 64 + c4;
            const uint2 va = ya[i], vb = yb[i];
            hb[w][c4 + 0] = fmaxf(fmaf(scp[0], (scp[0] > 0.f) ? bflo(va.x) : bflo(vb.x), shp[0]), 0.f);
            hb[w][c4 + 1] = fmaxf(fmaf(scp[1], (scp[1] > 0.f) ? bfhi(va.x) : bfhi(vb.x), shp[1]), 0.f);
            hb[w][c4 + 2] = fmaxf(fmaf(scp[2], (scp[2] > 0.f) ? bflo(va.y) : bflo(vb.y), shp[2]), 0.f);
            hb[w][c4 + 3] = fmaxf(fmaf(scp[3], (scp[3] > 0.f) ? bfhi(va.y) : bfhi(vb.y), shp[3]), 0.f);
        }
        __syncthreads();
        float s = 0.f;
        for (int w = grp * 32; w < grp * 32 + 32; ++w) s += hb[w][c];
        red[grp][c] = s;
        __syncthreads();
        if (tid < 64) mrow[tid] = (red[0][tid] + red[1][tid] + red[2][tid] + red[3][tid]) / 128.f;
        __syncthreads();
        const float m = mrow[c];
        float q = 0.f;
        for (int w = grp * 32; w < grp * 32 + 32; ++w) { const float d = hb[w][c] - m; q += d * d; }
        red[grp][c] = q;
        __syncthreads();
        if (tid < 64) {
            const float n2 = red[0][tid] + red[1][tid] + red[2][tid] + red[3][tid];
            const float n = fmaxf(sqrtf(n2), 1e-12f);
            const float m0 = mrow[tid];
            const float h0 = (hb[0][tid] - m0) / n, h1 = (hb[1][tid] - m0) / n;
            const float hN1 = (hb[127][tid] - m0) / n, hN2 = (hb[126][tid] - m0) / n;
            float* o = Sv + ((long long)b * 64 + tid) * 5;
            o[0] = -(hN2 + hN1); o[1] = -hN1; o[2] = 0.f; o[3] = -h0; o[4] = -(h0 + h1);
        }
    }
}

// fused similarity + per-row log-softmax diag + (last block) final reduce.
__global__ void simdot_nce(const float* __restrict__ kn, const float* __restrict__ Sv,
                           const float* __restrict__ ab, float* __restrict__ lp,
                           unsigned* __restrict__ counter, float* __restrict__ out)
{
    const int j = threadIdx.x;
    const int i = blockIdx.x;
    const int z = blockIdx.y;
    const float* a;
    const float* b;
    float coef;
    if (z == 0)      { a = kn + (long long)i * 320;         b = Sv + (long long)(256 + j) * 320; coef = 10.f / 128.f; }
    else if (z == 1) { a = kn + (long long)(256 + i) * 320; b = Sv + (long long)j * 320;         coef = 10.f / 128.f; }
    else             { a = ab + (long long)i * 320;         b = ab + (long long)(256 + j) * 320; coef = 10.f; }
    const float4* a4 = (const float4*)a;
    const float4* b4 = (const float4*)b;
    float acc = 0.f;
#pragma unroll 8
    for (int d = 0; d < 80; ++d) {
        const float4 xv = a4[d], yv = b4[d];
        acc += xv.x * yv.x + xv.y * yv.y + xv.z * yv.z + xv.w * yv.w;
    }
    const float v = acc * coef;

    __shared__ float red[NTHR];
    __shared__ float sdiag;
    if (j == i) sdiag = v;
    red[j] = v;
    __syncthreads();
    for (int off = NTHR / 2; off > 0; off >>= 1) {
        if (j < off) red[j] = fmaxf(red[j], red[j + off]);
        __syncthreads();
    }
    const float mx = red[0];
    __syncthreads();
    red[j] = expf(v - mx);
    __syncthreads();
    for (int off = NTHR / 2; off > 0; off >>= 1) {
        if (j < off) red[j] += red[j + off];
        __syncthreads();
    }
    if (j == 0) lp[z * 256 + i] = sdiag - (mx + logf(red[0]));

    // last block: reduce lp -> final loss
    __threadfence();
    __syncthreads();
    __shared__ unsigned done_s;
    if (j == 0)
        done_s = __hip_atomic_fetch_add(counter, 1u, __ATOMIC_ACQ_REL, __HIP_MEMORY_SCOPE_AGENT);
    __syncthreads();
    if (done_s != 767u) return;
    __threadfence();
    float l[3];
    for (int zz = 0; zz < 3; ++zz) {
        red[j] = lp[zz * 256 + j];
        __syncthreads();
        for (int off = NTHR / 2; off > 0; off >>= 1) {
            if (j < off) red[j] += red[j + off];
            __syncthreads();
        }
        l[zz] = red[0];
        __syncthreads();
    }
    if (j == 0) {
        out[0] = 0.5f * (-l[0] / 256.f - l[1] / 256.f) + 0.5f * (-l[2] / 256.f);
        __hip_atomic_store(counter, 0u, __ATOMIC_RELEASE, __HIP_MEMORY_SCOPE_AGENT);
    }
}

// ---------------------------------------------------------------------------

extern "C" void kernel_launch(void* const* d_in, const int* in_sizes, int n_in,
                              void* d_out, int out_size, void* d_ws, size_t ws_size,
                              hipStream_t stream)
{
    const float* x1  = (const float*)d_in[0];
    const float* x2  = (const float*)d_in[1];
    const float* w1  = (const float*)d_in[2];
    const float* b1  = (const float*)d_in[3];
    const float* g1  = (const float*)d_in[4];
    const float* be1 = (const float*)d_in[5];
    const float* w2  = (const float*)d_in[6];
    const float* b2  = (const float*)d_in[7];
    const float* g2  = (const float*)d_in[8];
    const float* be2 = (const float*)d_in[9];
    const float* w3  = (const float*)d_in[10];
    const float* b3  = (const float*)d_in[11];
    const float* g3  = (const float*)d_in[12];
    const float* be3 = (const float*)d_in[13];
    const float* tw1 = (const float*)d_in[14];
    const float* tb1 = (const float*)d_in[15];
    const float* tg1 = (const float*)d_in[16];
    const float* tbe1= (const float*)d_in[17];
    const float* tw2 = (const float*)d_in[18];
    const float* tb2 = (const float*)d_in[19];
    const float* tg2 = (const float*)d_in[20];
    const float* tbe2= (const float*)d_in[21];
    float* out = (float*)d_out;

    char* ws = (char*)d_ws;
    size_t off = 0;
    auto alloc = [&](size_t bytes) -> void* {
        off = (off + 255) & ~(size_t)255;
        void* p = ws + off;
        off += bytes;
        return p;
    };
    typedef unsigned short u16;
    u16* xT2   = (u16*)alloc((size_t)BSZ2 * 2048 * 16 * 2);
    u16* yMax2 = (u16*)alloc((size_t)BSZ2 * 512 * 32 * 2);
    u16* yMin2 = (u16*)alloc((size_t)BSZ2 * 512 * 32 * 2);
    u16* yMax3 = (u16*)alloc((size_t)BSZ2 * 128 * 64 * 2);
    u16* yMin3 = (u16*)alloc((size_t)BSZ2 * 128 * 64 * 2);
    u16* yT1   = (u16*)alloc((size_t)BSZ2 * 128 * 64 * 2);
    u16* yT2b  = (u16*)alloc((size_t)BSZ2 * 128 * 64 * 2);
    u16* wp2  = (u16*)alloc((size_t)9 * 1 * 2 * 512 * 2);
    u16* wp3  = (u16*)alloc((size_t)17 * 1 * 4 * 512 * 2);
    u16* wpt1 = (u16*)alloc((size_t)5 * 2 * 4 * 512 * 2);
    u16* wpt2 = (u16*)alloc((size_t)3 * 2 * 4 * 512 * 2);
    float* kn   = (float*)alloc((size_t)BSZ2 * 320 * 4);
    float* ab   = (float*)alloc((size_t)BSZ2 * 320 * 4);
    float* Sv   = (float*)alloc((size_t)BSZ2 * 320 * 4);
    float* lp   = (float*)alloc((size_t)3 * 256 * 4);
    float* pT   = (float*)alloc((size_t)128 * PSTRIDE * 4);   // 2 MB transposed partials
    float* scales = (float*)alloc((size_t)5 * 128 * 4);
    float* shifts = (float*)alloc((size_t)5 * 128 * 4);
    unsigned* counters = (unsigned*)alloc(6 * 4);
    float* sc1 = scales + 0 * 128, * sh1 = shifts + 0 * 128;
    float* sc2 = scales + 1 * 128, * sh2 = shifts + 1 * 128;
    float* sc3 = scales + 2 * 128, * sh3 = shifts + 2 * 128;
    float* sct1 = scales + 3 * 128, * sht1 = shifts + 3 * 128;
    float* sct2 = scales + 4 * 128, * sht2 = shifts + 4 * 128;

    hipMemsetAsync(counters, 0, 6 * sizeof(unsigned), stream);

    // ---- stage 1: stats(+packs, self-finalize) -> apply(pool) ----
    {
        const int nblk = BSZ2 * (8192 / 1024);    // WT=16 -> 4096 blocks
        conv1_mfma<16, 0><<<nblk, 256, 0, stream>>>(
            x1, x2, w1, b1, g1, be1, sc1, sh1, nullptr,
            pT, counters + 0, 1.f / (256.f * 8192.f),
            w2, w3, tw1, tw2, wp2, wp3, wpt1, wpt2);
        conv1_mfma<16, 1><<<nblk, 256, 0, stream>>>(
            x1, x2, w1, b1, nullptr, nullptr, sc1, sh1, xT2,
            nullptr, nullptr, 0.f,
            nullptr, nullptr, nullptr, nullptr, nullptr, nullptr, nullptr, nullptr);
    }
    // ---- stage 2: conv + stats + pooled minmax (CHUNK=512, self-finalize) ----
    conv_mfma2<16,32,17,8,2,9,1,2,8, 0,1><<<BSZ2 * (2048/512), 256, 0, stream>>>(
        xT2, nullptr, nullptr, nullptr, wp2, b2, yMax2, yMin2,
        g2, be2, sc2, sh2, pT, counters + 1, 1.f / (256.f * 2048.f), 2048);
    // ---- stage 3: stage-from-minmax(BN2) + conv + pooled minmax ----
    conv_mfma2<32,64,17,8,1,17,1,4,4, 1,1><<<BSZ2 * (512/256), 256, 0, stream>>>(
        yMax2, yMin2, sc2, sh2, wp3, b3, yMax3, yMin3,
        g3, be3, sc3, sh3, pT, counters + 2, 1.f / (256.f * 512.f), 512);
    // ---- template stage 1 ----
    conv_mfma2<64,64,5,2,1,5,2,4,2, 1,0><<<BSZ2, 256, 0, stream>>>(
        yMax3, yMin3, sc3, sh3, wpt1, tb1, yT1, nullptr,
        tg1, tbe1, sct1, sht1, pT, counters + 3, 1.f / (256.f * 128.f), 128);
    // ---- template stage 2 ----
    conv_mfma2<64,64,3,1,1,3,2,4,2, 2,0><<<BSZ2, 256, 0, stream>>>(
        yT1, nullptr, sct1, sht1, wpt2, tb2, yT2b, nullptr,
        tg2, tbe2, sct2, sht2, pT, counters + 4, 1.f / (256.f * 128.f), 128);

    // ---- tail + fused similarity/loss ----
    tail_pool_srow<<<2 * BSZ2, 256, 0, stream>>>(yT2b, sct2, sht2, yMax3, yMin3, sc3, sh3, kn, ab, Sv);
    dim3 sg(256, 3);
    simdot_nce<<<sg, NTHR, 0, stream>>>(kn, Sv, ab, lp, counters + 5, out);
}

// Round 14
// 204.314 us; speedup vs baseline: 6.2891x; 6.2891x over previous
//
#include <hip/hip_runtime.h>
#include <hip/hip_bf16.h>
#include <math.h>

// ---------------------------------------------------------------------------
// TCCL model forward. Round 13 = R11 (198us, passing) + fence-free R12 wins:
//  - build_all_wpacks kernel deleted; packs built by blocks 0..299 of the
//    stage-1 stats kernel (consumed 2 kernels later)
//  - stage-1 weight fragment read per-lane directly from w1 (L1-resident)
//  - R12's last-block finalize REVERTED: device-scope threadfence per block
//    serialized the 8 XCD L2s (conv1 stats 419us @ VALUBusy 3.3%) -> separate
//    finalize2 kernels restored.
// ---------------------------------------------------------------------------

#define BSZ2 512          // combined batch (x1 ++ x2)
#define NTHR 256

typedef __attribute__((ext_vector_type(8))) short bf16x8;
typedef __attribute__((ext_vector_type(4))) float f32x4;

__device__ __forceinline__ unsigned short f2bf(float f) {
    unsigned u = __float_as_uint(f);
    u = (u + 0x7FFFu + ((u >> 16) & 1u)) >> 16;
    return (unsigned short)u;
}
__device__ __forceinline__ float bflo(unsigned u) { return __uint_as_float(u << 16); }
__device__ __forceinline__ float bfhi(unsigned u) { return __uint_as_float(u & 0xFFFF0000u); }

// ---------------- weight prepack helper --------------------------------------
template<int CIN, int KK, int DT, int NP, int S, int CT>
__device__ __forceinline__ void pack_one(int idx, const float* __restrict__ wgt,
                                         unsigned short* __restrict__ wp)
{
    const int j = idx & 7;
    const int l = (idx >> 3) & 63;
    int rest = idx >> 9;
    const int ct = rest % CT; rest /= CT;
    const int s = rest % S;
    const int p = rest / S;
    const int co = ct * 16 + (l & 15);
    const int k = (l >> 4) * 8 + j;
    int ci, t;
    if (DT == 2) { ci = k & (CIN - 1); t = p * 2 + (k >> 4); }
    else         { ci = s * 32 + k;    t = p; }
    float v = (t < KK) ? wgt[((long long)co * CIN + ci) * KK + t] : 0.f;
    wp[idx] = f2bf(v);
}

// ---------------- stage 1 MFMA conv (Cin=1, K=17 padded to 32) --------------
// swapped operands: D[w][co], co = lane&15, w = kq*4+e (register axis pool)
// MODE 0 = stats partials (+ pack duty); MODE 1 = BN+ReLU+maxpool4
template<int WT, int MODE>
__global__ __launch_bounds__(256)
void conv1_mfma(const float* __restrict__ x1, const float* __restrict__ x2,
                const float* __restrict__ w1, const float* __restrict__ bias,
                const float* __restrict__ scale, const float* __restrict__ shift,
                unsigned short* __restrict__ out, float* __restrict__ partials,
                const float* __restrict__ w2, const float* __restrict__ w3,
                const float* __restrict__ tw1, const float* __restrict__ tw2,
                unsigned short* __restrict__ wp2, unsigned short* __restrict__ wp3,
                unsigned short* __restrict__ wpt1, unsigned short* __restrict__ wpt2)
{
    constexpr int W = 8192;
    constexpr int CHUNK = 4 * WT * 16;
    __shared__ float xs[CHUNK + 32];
    __shared__ float sred[(MODE == 0) ? 4 : 1][16];
    __shared__ float ssred[(MODE == 0) ? 4 : 1][16];

    const int tid = threadIdx.x;

    // pack duty (stats pass only; consumed 2 kernels later)
    if (MODE == 0 && blockIdx.x < 300) {
        const int idx = blockIdx.x * 256 + tid;   // < 76800
        const int n2 = 9216, n3 = 34816, nt1 = 20480;
        if (idx < n2) pack_one<16, 17, 2, 9, 1, 2>(idx, w2, wp2);
        else if (idx < n2 + n3) pack_one<32, 17, 1, 17, 1, 4>(idx - n2, w3, wp3);
        else if (idx < n2 + n3 + nt1) pack_one<64, 5, 1, 5, 2, 4>(idx - n2 - n3, tw1, wpt1);
        else if (idx < 76800) pack_one<64, 3, 1, 3, 2, 4>(idx - n2 - n3 - nt1, tw2, wpt2);
    }

    const int ntile = W / CHUNK;
    const int b = blockIdx.x / ntile;
    const int w0 = (blockIdx.x % ntile) * CHUNK;
    const float* xrow = (b < 256) ? x1 + (long long)b * W : x2 + (long long)(b - 256) * W;

    for (int i = tid; i < CHUNK + 32; i += 256) {
        const int gw = w0 - 8 + i;
        xs[i] = (gw >= 0 && gw < W) ? xrow[gw] : 0.f;
    }
    __syncthreads();

    const int lane = tid & 63, wave = tid >> 6;
    const int n = lane & 15, kq = lane >> 4;
    // weight fragment direct from w1 (1KB table, L1-resident): co=n, k=kq*8+j
    bf16x8 a;
#pragma unroll
    for (int j = 0; j < 8; ++j) {
        const int k = kq * 8 + j;
        const float wv = (k < 17) ? w1[n * 17 + k] : 0.f;
        __hip_bfloat16 h = __float2bfloat16(wv);
        a[j] = *reinterpret_cast<const short*>(&h);
    }

    f32x4 acc[WT];
#pragma unroll
    for (int wt = 0; wt < WT; ++wt) { acc[wt][0]=0.f; acc[wt][1]=0.f; acc[wt][2]=0.f; acc[wt][3]=0.f; }

    const int base0 = wave * WT * 16 + n + kq * 8;          // x frag: row w=n, k=kq*8+j
#pragma unroll
    for (int wt = 0; wt < WT; ++wt) {
        bf16x8 bv;
#pragma unroll
        for (int j = 0; j < 8; ++j) {
            __hip_bfloat16 h = __float2bfloat16(xs[base0 + wt * 16 + j]);
            bv[j] = *reinterpret_cast<const short*>(&h);
        }
        acc[wt] = __builtin_amdgcn_mfma_f32_16x16x32_bf16(bv, a, acc[wt], 0, 0, 0);  // D[w][co]
    }

    if (MODE == 0) {
        const float bi = bias[n];
        float s_ = 0.f, ss_ = 0.f;
#pragma unroll
        for (int wt = 0; wt < WT; ++wt)
#pragma unroll
            for (int e = 0; e < 4; ++e) {
                const float y = acc[wt][e] + bi;
                s_ += y; ss_ += y * y;
            }
        s_  += __shfl_xor(s_, 16, 64);  s_  += __shfl_xor(s_, 32, 64);
        ss_ += __shfl_xor(ss_, 16, 64); ss_ += __shfl_xor(ss_, 32, 64);
        if (lane < 16) { sred[wave][n] = s_; ssred[wave][n] = ss_; }
        __syncthreads();
        if (tid < 16) {
            float sumv = 0.f, sumsq = 0.f;
#pragma unroll
            for (int wv = 0; wv < 4; ++wv) { sumv += sred[wv][tid]; sumsq += ssred[wv][tid]; }
            partials[((long long)blockIdx.x * 16 + tid) * 2 + 0] = sumv;
            partials[((long long)blockIdx.x * 16 + tid) * 2 + 1] = sumsq;
        }
    } else {
        const int half = b >> 8;
        const float bi = bias[n];
        const float scv = scale[half * 16 + n];
        const float shv = shift[half * 16 + n];
#pragma unroll
        for (int wt = 0; wt < WT; ++wt) {
            float v[4];
#pragma unroll
            for (int e = 0; e < 4; ++e) v[e] = fmaf(scv, acc[wt][e] + bi, shv);
            const float mx = fmaxf(fmaxf(fmaxf(v[0], v[1]), fmaxf(v[2], v[3])), 0.f);
            const int wp = (w0 >> 2) + wave * WT * 4 + wt * 4 + kq;
            out[((long long)b * 2048 + wp) * 16 + n] = f2bf(mx);
        }
    }
}

// per-channel, per-half finalize. grid (COUT, 2).
template<int COUT>
__global__ void finalize2(const float* __restrict__ partials, int nblk_half, float invN,
                          const float* __restrict__ g, const float* __restrict__ be,
                          float* __restrict__ scale, float* __restrict__ shift)
{
    const int co = blockIdx.x;
    const int half = blockIdx.y;
    const float* P = partials + (size_t)half * nblk_half * COUT * 2;
    float s = 0.f, ss = 0.f;
    for (int i = threadIdx.x; i < nblk_half; i += NTHR) {
        s  += P[((long long)i * COUT + co) * 2 + 0];
        ss += P[((long long)i * COUT + co) * 2 + 1];
    }
    __shared__ float red[NTHR][2];
    red[threadIdx.x][0] = s; red[threadIdx.x][1] = ss;
    __syncthreads();
    for (int off = NTHR / 2; off > 0; off >>= 1) {
        if ((int)threadIdx.x < off) {
            red[threadIdx.x][0] += red[threadIdx.x + off][0];
            red[threadIdx.x][1] += red[threadIdx.x + off][1];
        }
        __syncthreads();
    }
    if (threadIdx.x == 0) {
        const float m = red[0][0] * invN;
        const float v = red[0][1] * invN - m * m;
        const float inv = rsqrtf(v + 1e-5f);
        const float sc = g[co] * inv;
        scale[half * COUT + co] = sc;
        shift[half * COUT + co] = be[co] - sc * m;
    }
}

// ---------------- MFMA conv, generalized (swapped operands) -----------------
// D[w][co]: co = ct*16 + (lane&15), w = w0 + wave*ST*16 + st*16 + kq*4 + e
// SRCM: 0 = src bf16 as-is; 1 = (max,min) pair + prev BN select + relu;
//       2 = raw y + prev BN + relu
// OUTM: 0 = store raw y; 1 = store pooled (max,min) of raw y
template<int CIN, int COUT, int KK, int PAD, int DT, int NP, int S, int CT, int ST,
         int SRCM, int OUTM>
__global__ __launch_bounds__(256)
void conv_mfma2(const unsigned short* __restrict__ xA, const unsigned short* __restrict__ xB,
                const float* __restrict__ pscale, const float* __restrict__ pshift,
                const unsigned short* __restrict__ wpack, const float* __restrict__ bias,
                unsigned short* __restrict__ outA, unsigned short* __restrict__ outB,
                float* __restrict__ partials, int W)
{
    constexpr int CHUNK = 4 * ST * 16;
    constexpr int ROWB = CIN * 2 + 16;
    constexpr int ROWS = CHUNK + KK + (DT - 1) + 1;
    constexpr int DPR = CIN / 2;
    __shared__ __align__(16) unsigned char lx[ROWS * ROWB];
    __shared__ float sred[4][CT][16];
    __shared__ float ssred[4][CT][16];
    __shared__ float scb[(SRCM > 0) ? CIN : 1];
    __shared__ float shb[(SRCM > 0) ? CIN : 1];

    const int tid = threadIdx.x;
    const int ntile = W / CHUNK;
    const int b = blockIdx.x / ntile;
    const int tile = blockIdx.x % ntile;
    const int w0 = tile * CHUNK;

    if (SRCM > 0) {
        if (tid < CIN) {
            scb[tid] = pscale[(b >> 8) * CIN + tid];
            shb[tid] = pshift[(b >> 8) * CIN + tid];
        }
        __syncthreads();
    }

    for (int d = tid; d < ROWS * DPR; d += 256) {
        const int row = d / DPR;
        const int col = d % DPR;
        const int gw = w0 - PAD + row;
        unsigned v = 0;
        if (gw >= 0 && gw < W) {
            const long long src = ((long long)b * W + gw) * CIN + col * 2;
            if (SRCM == 0) {
                v = *(const unsigned*)(xA + src);
            } else {
                const unsigned va = *(const unsigned*)(xA + src);
                const float sc0 = scb[col * 2], sh0 = shb[col * 2];
                const float sc1 = scb[col * 2 + 1], sh1 = shb[col * 2 + 1];
                float f0, f1;
                if (SRCM == 1) {
                    const unsigned vb = *(const unsigned*)(xB + src);
                    f0 = fmaxf(fmaf(sc0, (sc0 > 0.f) ? bflo(va) : bflo(vb), sh0), 0.f);
                    f1 = fmaxf(fmaf(sc1, (sc1 > 0.f) ? bfhi(va) : bfhi(vb), sh1), 0.f);
                } else {
                    f0 = fmaxf(fmaf(sc0, bflo(va), sh0), 0.f);
                    f1 = fmaxf(fmaf(sc1, bfhi(va), sh1), 0.f);
                }
                v = (unsigned)f2bf(f0) | ((unsigned)f2bf(f1) << 16);
            }
        }
        *(unsigned*)(lx + row * ROWB + col * 4) = v;
    }
    __syncthreads();

    const int lane = tid & 63, wave = tid >> 6;
    const int n = lane & 15, kq = lane >> 4;
    int rowbase, cbyte;
    if (DT == 2) { rowbase = wave * ST * 16 + n + (kq >> 1); cbyte = (kq & 1) * 16; }
    else         { rowbase = wave * ST * 16 + n;             cbyte = kq * 16; }

    f32x4 acc[ST][CT];
#pragma unroll
    for (int st = 0; st < ST; ++st)
#pragma unroll
        for (int ct = 0; ct < CT; ++ct) { acc[st][ct][0]=0.f; acc[st][ct][1]=0.f; acc[st][ct][2]=0.f; acc[st][ct][3]=0.f; }

#pragma unroll
    for (int p = 0; p < NP; ++p) {
#pragma unroll
        for (int s = 0; s < S; ++s) {
            bf16x8 a[CT];
#pragma unroll
            for (int ct = 0; ct < CT; ++ct)
                a[ct] = *(const bf16x8*)(wpack + (((long long)(p * S + s) * CT + ct) * 64 + lane) * 8);
#pragma unroll
            for (int st = 0; st < ST; ++st) {
                const int r = rowbase + st * 16 + p * DT;
                const bf16x8 bf = *(const bf16x8*)(lx + r * ROWB + cbyte + s * 64);
#pragma unroll
                for (int ct = 0; ct < CT; ++ct)
                    acc[st][ct] = __builtin_amdgcn_mfma_f32_16x16x32_bf16(bf, a[ct], acc[st][ct], 0, 0, 0);
            }
        }
    }

    // epilogue: D[w][co] -> pool over register axis; per-lane scalar stores
    float s_[CT], ss_[CT];
#pragma unroll
    for (int ct = 0; ct < CT; ++ct) { s_[ct] = 0.f; ss_[ct] = 0.f; }

#pragma unroll
    for (int st = 0; st < ST; ++st) {
        const int wbase = w0 + wave * ST * 16 + st * 16 + kq * 4;
#pragma unroll
        for (int ct = 0; ct < CT; ++ct) {
            const float bi = bias[ct * 16 + n];
            float v[4];
#pragma unroll
            for (int e = 0; e < 4; ++e) {
                v[e] = acc[st][ct][e] + bi;
                s_[ct] += v[e];
                ss_[ct] += v[e] * v[e];
            }
            if (OUTM == 0) {
#pragma unroll
                for (int e = 0; e < 4; ++e)
                    outA[((long long)b * W + wbase + e) * COUT + ct * 16 + n] = f2bf(v[e]);
            } else {
                const float mx = fmaxf(fmaxf(v[0], v[1]), fmaxf(v[2], v[3]));
                const float mn = fminf(fminf(v[0], v[1]), fminf(v[2], v[3]));
                const long long o = ((long long)b * (W >> 2) + (wbase >> 2)) * COUT + ct * 16 + n;
                outA[o] = f2bf(mx);
                outB[o] = f2bf(mn);
            }
        }
    }
#pragma unroll
    for (int ct = 0; ct < CT; ++ct) {
        s_[ct]  += __shfl_xor(s_[ct], 16, 64);  s_[ct]  += __shfl_xor(s_[ct], 32, 64);
        ss_[ct] += __shfl_xor(ss_[ct], 16, 64); ss_[ct] += __shfl_xor(ss_[ct], 32, 64);
    }
    if (lane < 16) {
#pragma unroll
        for (int ct = 0; ct < CT; ++ct) { sred[wave][ct][n] = s_[ct]; ssred[wave][ct][n] = ss_[ct]; }
    }
    __syncthreads();
    if (tid < COUT) {
        const int ct = tid >> 4, nn = tid & 15;
        float sumv = 0.f, sumsq = 0.f;
#pragma unroll
        for (int wv = 0; wv < 4; ++wv) { sumv += sred[wv][ct][nn]; sumsq += ssred[wv][ct][nn]; }
        partials[((long long)blockIdx.x * COUT + tid) * 2 + 0] = sumv;
        partials[((long long)blockIdx.x * COUT + tid) * 2 + 1] = sumsq;
    }
}

// ---------------- fused tail --------------------------------------------------
// blocks [0,512): BN+ReLU+adapool5 from raw y_t2, then IN-BLOCK flatnorm (ab)
//                 and knorm (kn).
// blocks [512,1024): h from stage3 minmax + BN select, center+norm -> Sv.
__global__ void tail_pool_srow(const unsigned short* __restrict__ yT2b,
                               const float* __restrict__ scT2, const float* __restrict__ shT2,
                               const unsigned short* __restrict__ yMax3,
                               const unsigned short* __restrict__ yMin3,
                               const float* __restrict__ scS3, const float* __restrict__ shS3,
                               float* __restrict__ kn, float* __restrict__ ab,
                               float* __restrict__ Sv)
{
    __shared__ float hb[128][64];
    const int tid = threadIdx.x;
    if (blockIdx.x < BSZ2) {
        const int b = blockIdx.x;
        __shared__ float pk[320];
        __shared__ float red2[NTHR];
        const uint2* yd = (const uint2*)(yT2b + (long long)b * 128 * 64);
        for (int i = tid; i < 128 * 16; i += 256) {
            const int w = i >> 4, c4 = (i & 15) * 4;
            const float* scp = scT2 + (b >> 8) * 64 + c4;
            const float* shp = shT2 + (b >> 8) * 64 + c4;
            const uint2 v = yd[i];
            hb[w][c4 + 0] = fmaxf(fmaf(scp[0], bflo(v.x), shp[0]), 0.f);
            hb[w][c4 + 1] = fmaxf(fmaf(scp[1], bfhi(v.x), shp[1]), 0.f);
            hb[w][c4 + 2] = fmaxf(fmaf(scp[2], bflo(v.y), shp[2]), 0.f);
            hb[w][c4 + 3] = fmaxf(fmaf(scp[3], bfhi(v.y), shp[3]), 0.f);
        }
        __syncthreads();
        const int bs[5] = {0, 25, 51, 76, 102};
        const int be5[5] = {26, 52, 77, 103, 128};
        for (int o = tid; o < 320; o += 256) {
            const int cc = o & 63, bin = o >> 6;
            float acc = 0.f;
            for (int w = bs[bin]; w < be5[bin]; ++w) acc += hb[w][cc];
            pk[cc * 5 + bin] = acc / (float)(be5[bin] - bs[bin]);
        }
        __syncthreads();
        float n2p = pk[tid] * pk[tid];
        if (tid < 64) n2p += pk[256 + tid] * pk[256 + tid];
        red2[tid] = n2p;
        __syncthreads();
        for (int off = NTHR / 2; off > 0; off >>= 1) {
            if (tid < off) red2[tid] += red2[tid + off];
            __syncthreads();
        }
        const float nrm = fmaxf(sqrtf(red2[0]), 1e-12f);
        for (int i = tid; i < 320; i += 256) ab[(long long)b * 320 + i] = pk[i] / nrm;
        if (tid < 64) {
            const float* p = pk + tid * 5;
            float m = 0.f;
            for (int t = 0; t < 5; ++t) m += p[t];
            m *= 0.2f;
            float v[5]; float q = 0.f;
            for (int t = 0; t < 5; ++t) { v[t] = p[t] - m; q += v[t] * v[t]; }
            const float n = fmaxf(sqrtf(q), 1e-12f);
            float* o = kn + ((long long)b * 64 + tid) * 5;
            for (int t = 0; t < 5; ++t) o[t] = v[t] / n;
        }
    } else {
        __shared__ float red[4][64];
        __shared__ float mrow[64];
        const int b = blockIdx.x - BSZ2;
        const int c = tid & 63, grp = tid >> 6;
        const uint2* ya = (const uint2*)(yMax3 + (long long)b * 128 * 64);
        const uint2* yb = (const uint2*)(yMin3 + (long long)b * 128 * 64);
        for (int i = tid; i < 128 * 16; i += 256) {
            const int w = i >> 4, c4 = (i & 15) * 4;
            const float* scp = scS3 + (b >> 8) * 64 + c4;
            const float* shp = shS3 + (b >> 8) * 64 + c4;
            const uint2 va = ya[i], vb = yb[i];
            hb[w][c4 + 0] = fmaxf(fmaf(scp[0], (scp[0] > 0.f) ? bflo(va.x) : bflo(vb.x), shp[0]), 0.f);
            hb[w][c4 + 1] = fmaxf(fmaf(scp[1], (scp[1] > 0.f) ? bfhi(va.x) : bfhi(vb.x), shp[1]), 0.f);
            hb[w][c4 + 2] = fmaxf(fmaf(scp[2], (scp[2] > 0.f) ? bflo(va.y) : bflo(vb.y), shp[2]), 0.f);
            hb[w][c4 + 3] = fmaxf(fmaf(scp[3], (scp[3] > 0.f) ? bfhi(va.y) : bfhi(vb.y), shp[3]), 0.f);
        }
        __syncthreads();
        float s = 0.f;
        for (int w = grp * 32; w < grp * 32 + 32; ++w) s += hb[w][c];
        red[grp][c] = s;
        __syncthreads();
        if (tid < 64) mrow[tid] = (red[0][tid] + red[1][tid] + red[2][tid] + red[3][tid]) / 128.f;
        __syncthreads();
        const float m = mrow[c];
        float q = 0.f;
        for (int w = grp * 32; w < grp * 32 + 32; ++w) { const float d = hb[w][c] - m; q += d * d; }
        red[grp][c] = q;
        __syncthreads();
        if (tid < 64) {
            const float n2 = red[0][tid] + red[1][tid] + red[2][tid] + red[3][tid];
            const float n = fmaxf(sqrtf(n2), 1e-12f);
            const float m0 = mrow[tid];
            const float h0 = (hb[0][tid] - m0) / n, h1 = (hb[1][tid] - m0) / n;
            const float hN1 = (hb[127][tid] - m0) / n, hN2 = (hb[126][tid] - m0) / n;
            float* o = Sv + ((long long)b * 64 + tid) * 5;
            o[0] = -(hN2 + hN1); o[1] = -hN1; o[2] = 0.f; o[3] = -h0; o[4] = -(h0 + h1);
        }
    }
}

// fused similarity + per-row log-softmax diag. grid (256, 3), block 256.
__global__ void simdot_nce(const float* __restrict__ kn, const float* __restrict__ Sv,
                           const float* __restrict__ ab, float* __restrict__ lp)
{
    const int j = threadIdx.x;
    const int i = blockIdx.x;
    const int z = blockIdx.y;
    const float* a;
    const float* b;
    float coef;
    if (z == 0)      { a = kn + (long long)i * 320;         b = Sv + (long long)(256 + j) * 320; coef = 10.f / 128.f; }
    else if (z == 1) { a = kn + (long long)(256 + i) * 320; b = Sv + (long long)j * 320;         coef = 10.f / 128.f; }
    else             { a = ab + (long long)i * 320;         b = ab + (long long)(256 + j) * 320; coef = 10.f; }
    const float4* a4 = (const float4*)a;
    const float4* b4 = (const float4*)b;
    float acc = 0.f;
#pragma unroll 8
    for (int d = 0; d < 80; ++d) {
        const float4 xv = a4[d], yv = b4[d];
        acc += xv.x * yv.x + xv.y * yv.y + xv.z * yv.z + xv.w * yv.w;
    }
    const float v = acc * coef;

    __shared__ float red[NTHR];
    __shared__ float sdiag;
    if (j == i) sdiag = v;
    red[j] = v;
    __syncthreads();
    for (int off = NTHR / 2; off > 0; off >>= 1) {
        if (j < off) red[j] = fmaxf(red[j], red[j + off]);
        __syncthreads();
    }
    const float mx = red[0];
    __syncthreads();
    red[j] = expf(v - mx);
    __syncthreads();
    for (int off = NTHR / 2; off > 0; off >>= 1) {
        if (j < off) red[j] += red[j + off];
        __syncthreads();
    }
    if (j == 0) lp[z * 256 + i] = sdiag - (mx + logf(red[0]));
}

// reduce lp -> final loss scalar
__global__ void final3(const float* __restrict__ lp, float* __restrict__ out)
{
    __shared__ float red[NTHR];
    const int tid = threadIdx.x;
    float l[3];
    for (int z = 0; z < 3; ++z) {
        red[tid] = lp[z * 256 + tid];
        __syncthreads();
        for (int off = NTHR / 2; off > 0; off >>= 1) {
            if (tid < off) red[tid] += red[tid + off];
            __syncthreads();
        }
        l[z] = red[0];
        __syncthreads();
    }
    if (tid == 0)
        out[0] = 0.5f * (-l[0] / 256.f - l[1] / 256.f) + 0.5f * (-l[2] / 256.f);
}

// ---------------------------------------------------------------------------

extern "C" void kernel_launch(void* const* d_in, const int* in_sizes, int n_in,
                              void* d_out, int out_size, void* d_ws, size_t ws_size,
                              hipStream_t stream)
{
    const float* x1  = (const float*)d_in[0];
    const float* x2  = (const float*)d_in[1];
    const float* w1  = (const float*)d_in[2];
    const float* b1  = (const float*)d_in[3];
    const float* g1  = (const float*)d_in[4];
    const float* be1 = (const float*)d_in[5];
    const float* w2  = (const float*)d_in[6];
    const float* b2  = (const float*)d_in[7];
    const float* g2  = (const float*)d_in[8];
    const float* be2 = (const float*)d_in[9];
    const float* w3  = (const float*)d_in[10];
    const float* b3  = (const float*)d_in[11];
    const float* g3  = (const float*)d_in[12];
    const float* be3 = (const float*)d_in[13];
    const float* tw1 = (const float*)d_in[14];
    const float* tb1 = (const float*)d_in[15];
    const float* tg1 = (const float*)d_in[16];
    const float* tbe1= (const float*)d_in[17];
    const float* tw2 = (const float*)d_in[18];
    const float* tb2 = (const float*)d_in[19];
    const float* tg2 = (const float*)d_in[20];
    const float* tbe2= (const float*)d_in[21];
    float* out = (float*)d_out;

    char* ws = (char*)d_ws;
    size_t off = 0;
    auto alloc = [&](size_t bytes) -> void* {
        off = (off + 255) & ~(size_t)255;
        void* p = ws + off;
        off += bytes;
        return p;
    };
    typedef unsigned short u16;
    u16* xT2   = (u16*)alloc((size_t)BSZ2 * 2048 * 16 * 2);  // stage1 out   33.6MB
    u16* yMax2 = (u16*)alloc((size_t)BSZ2 * 512 * 32 * 2);   // 16.8MB
    u16* yMin2 = (u16*)alloc((size_t)BSZ2 * 512 * 32 * 2);   // 16.8MB
    u16* yMax3 = (u16*)alloc((size_t)BSZ2 * 128 * 64 * 2);   //  8.4MB
    u16* yMin3 = (u16*)alloc((size_t)BSZ2 * 128 * 64 * 2);   //  8.4MB
    u16* yT1   = (u16*)alloc((size_t)BSZ2 * 128 * 64 * 2);   //  8.4MB
    u16* yT2b  = (u16*)alloc((size_t)BSZ2 * 128 * 64 * 2);   //  8.4MB
    u16* wp2  = (u16*)alloc((size_t)9 * 1 * 2 * 512 * 2);
    u16* wp3  = (u16*)alloc((size_t)17 * 1 * 4 * 512 * 2);
    u16* wpt1 = (u16*)alloc((size_t)5 * 2 * 4 * 512 * 2);
    u16* wpt2 = (u16*)alloc((size_t)3 * 2 * 4 * 512 * 2);
    float* kn   = (float*)alloc((size_t)BSZ2 * 320 * 4);
    float* ab   = (float*)alloc((size_t)BSZ2 * 320 * 4);
    float* Sv   = (float*)alloc((size_t)BSZ2 * 320 * 4);
    float* lp   = (float*)alloc((size_t)3 * 256 * 4);
    float* partials = (float*)alloc((size_t)16384 * 16 * 2 * 4);  // 2 MB
    float* scales = (float*)alloc((size_t)5 * 128 * 4);           // per-stage [2][C]
    float* shifts = (float*)alloc((size_t)5 * 128 * 4);
    float* sc1 = scales + 0 * 128, * sh1 = shifts + 0 * 128;
    float* sc2 = scales + 1 * 128, * sh2 = shifts + 1 * 128;
    float* sc3 = scales + 2 * 128, * sh3 = shifts + 2 * 128;
    float* sct1 = scales + 3 * 128, * sht1 = shifts + 3 * 128;
    float* sct2 = scales + 4 * 128, * sht2 = shifts + 4 * 128;

    // ---- stage 1: stats(+packs) -> finalize -> apply(pool) ----
    {
        const int nblk = BSZ2 * (8192 / 512);    // WT=8 -> 8192 blocks
        conv1_mfma<8, 0><<<nblk, 256, 0, stream>>>(
            x1, x2, w1, b1, nullptr, nullptr, nullptr, partials,
            w2, w3, tw1, tw2, wp2, wp3, wpt1, wpt2);
        dim3 fg(16, 2);
        finalize2<16><<<fg, NTHR, 0, stream>>>(partials, nblk / 2, 1.f / (256.f * 8192.f), g1, be1, sc1, sh1);
        conv1_mfma<8, 1><<<nblk, 256, 0, stream>>>(
            x1, x2, w1, b1, sc1, sh1, xT2, nullptr,
            nullptr, nullptr, nullptr, nullptr, nullptr, nullptr, nullptr, nullptr);
    }
    // ---- stage 2: conv + stats + pooled minmax (CHUNK=512) ----
    {
        const int nblk = BSZ2 * (2048 / 512);
        conv_mfma2<16,32,17,8,2,9,1,2,8, 0,1><<<nblk, 256, 0, stream>>>(
            xT2, nullptr, nullptr, nullptr, wp2, b2, yMax2, yMin2, partials, 2048);
        dim3 fg(32, 2);
        finalize2<32><<<fg, NTHR, 0, stream>>>(partials, nblk / 2, 1.f / (256.f * 2048.f), g2, be2, sc2, sh2);
    }
    // ---- stage 3: stage-from-minmax(BN2) + conv + stats + pooled minmax ----
    {
        const int nblk = BSZ2 * (512 / 256);
        conv_mfma2<32,64,17,8,1,17,1,4,4, 1,1><<<nblk, 256, 0, stream>>>(
            yMax2, yMin2, sc2, sh2, wp3, b3, yMax3, yMin3, partials, 512);
        dim3 fg(64, 2);
        finalize2<64><<<fg, NTHR, 0, stream>>>(partials, nblk / 2, 1.f / (256.f * 512.f), g3, be3, sc3, sh3);
    }
    // ---- template stage 1: stage-from-minmax(BN3) + conv + stats + y ----
    {
        conv_mfma2<64,64,5,2,1,5,2,4,2, 1,0><<<BSZ2, 256, 0, stream>>>(
            yMax3, yMin3, sc3, sh3, wpt1, tb1, yT1, nullptr, partials, 128);
        dim3 fg(64, 2);
        finalize2<64><<<fg, NTHR, 0, stream>>>(partials, 256, 1.f / (256.f * 128.f), tg1, tbe1, sct1, sht1);
    }
    // ---- template stage 2: stage-from-y(BNt1) + conv + stats + y ----
    {
        conv_mfma2<64,64,3,1,1,3,2,4,2, 2,0><<<BSZ2, 256, 0, stream>>>(
            yT1, nullptr, sct1, sht1, wpt2, tb2, yT2b, nullptr, partials, 128);
        dim3 fg(64, 2);
        finalize2<64><<<fg, NTHR, 0, stream>>>(partials, 256, 1.f / (256.f * 128.f), tg2, tbe2, sct2, sht2);
    }

    // ---- tail: adapool+norms (blocks 0..511) + srow (512..1023) ----
    tail_pool_srow<<<2 * BSZ2, 256, 0, stream>>>(yT2b, sct2, sht2, yMax3, yMin3, sc3, sh3, kn, ab, Sv);
    dim3 sg(256, 3);
    simdot_nce<<<sg, NTHR, 0, stream>>>(kn, Sv, ab, lp);
    final3<<<1, NTHR, 0, stream>>>(lp, out);
}

// Round 15
// 190.808 us; speedup vs baseline: 6.7343x; 1.0708x over previous
//
#include <hip/hip_runtime.h>
#include <hip/hip_bf16.h>
#include <math.h>

// ---------------------------------------------------------------------------
// TCCL model forward. Round 14 = R11 (best measured, 198us) with stage-1
// switched to the pooled-minmax pattern:
//  - conv1 stats pass stores per-pool-window (max,min) of raw y (register-
//    local pool, no shuffles) -> conv1 APPLY PASS DELETED (64MB re-read +
//    33.6MB write + launch)
//  - stage 2 consumes minmax via the verified SRCM=1 BN-select staging
//  - R13's pack-in-stats / direct-w1 reverted (measured neutral-negative)
// 13 launches.
// ---------------------------------------------------------------------------

#define BSZ2 512          // combined batch (x1 ++ x2)
#define NTHR 256

typedef __attribute__((ext_vector_type(8))) short bf16x8;
typedef __attribute__((ext_vector_type(4))) float f32x4;

static inline int ceil_divll(long long a, int b) { return (int)((a + b - 1) / b); }

__device__ __forceinline__ unsigned short f2bf(float f) {
    unsigned u = __float_as_uint(f);
    u = (u + 0x7FFFu + ((u >> 16) & 1u)) >> 16;
    return (unsigned short)u;
}
__device__ __forceinline__ float bflo(unsigned u) { return __uint_as_float(u << 16); }
__device__ __forceinline__ float bfhi(unsigned u) { return __uint_as_float(u & 0xFFFF0000u); }

// ---------------- stage 1 MFMA conv (Cin=1, K=17 padded to 32) --------------
// D[w][co], co = lane&15, w = kq*4+e. Single pass: stats partials + pooled
// (max,min) of raw y -> bf16 [b][2048][16] x2.
template<int WT>
__global__ __launch_bounds__(256)
void conv1_mfma(const float* __restrict__ x1, const float* __restrict__ x2,
                const unsigned short* __restrict__ wpack1, const float* __restrict__ bias,
                unsigned short* __restrict__ outMax, unsigned short* __restrict__ outMin,
                float* __restrict__ partials)
{
    constexpr int W = 8192;
    constexpr int CHUNK = 4 * WT * 16;
    __shared__ float xs[CHUNK + 32];
    __shared__ float sred[4][16];
    __shared__ float ssred[4][16];

    const int tid = threadIdx.x;
    const int ntile = W / CHUNK;
    const int b = blockIdx.x / ntile;
    const int w0 = (blockIdx.x % ntile) * CHUNK;
    const float* xrow = (b < 256) ? x1 + (long long)b * W : x2 + (long long)(b - 256) * W;

    for (int i = tid; i < CHUNK + 32; i += 256) {
        const int gw = w0 - 8 + i;
        xs[i] = (gw >= 0 && gw < W) ? xrow[gw] : 0.f;
    }
    __syncthreads();

    const int lane = tid & 63, wave = tid >> 6;
    const int n = lane & 15, kq = lane >> 4;
    const bf16x8 a = *(const bf16x8*)(wpack1 + lane * 8);   // weights: co=n, k=kq*8+j

    f32x4 acc[WT];
#pragma unroll
    for (int wt = 0; wt < WT; ++wt) { acc[wt][0]=0.f; acc[wt][1]=0.f; acc[wt][2]=0.f; acc[wt][3]=0.f; }

    const int base0 = wave * WT * 16 + n + kq * 8;          // x frag: row w=n, k=kq*8+j
#pragma unroll
    for (int wt = 0; wt < WT; ++wt) {
        bf16x8 bv;
#pragma unroll
        for (int j = 0; j < 8; ++j) {
            __hip_bfloat16 h = __float2bfloat16(xs[base0 + wt * 16 + j]);
            bv[j] = *reinterpret_cast<const short*>(&h);
        }
        acc[wt] = __builtin_amdgcn_mfma_f32_16x16x32_bf16(bv, a, acc[wt], 0, 0, 0);  // D[w][co]
    }

    const float bi = bias[n];
    float s_ = 0.f, ss_ = 0.f;
#pragma unroll
    for (int wt = 0; wt < WT; ++wt) {
        float v[4];
#pragma unroll
        for (int e = 0; e < 4; ++e) {
            v[e] = acc[wt][e] + bi;
            s_ += v[e]; ss_ += v[e] * v[e];
        }
        const float mx = fmaxf(fmaxf(v[0], v[1]), fmaxf(v[2], v[3]));
        const float mn = fminf(fminf(v[0], v[1]), fminf(v[2], v[3]));
        const int wp = (w0 >> 2) + wave * WT * 4 + wt * 4 + kq;
        outMax[((long long)b * 2048 + wp) * 16 + n] = f2bf(mx);
        outMin[((long long)b * 2048 + wp) * 16 + n] = f2bf(mn);
    }
    s_  += __shfl_xor(s_, 16, 64);  s_  += __shfl_xor(s_, 32, 64);
    ss_ += __shfl_xor(ss_, 16, 64); ss_ += __shfl_xor(ss_, 32, 64);
    if (lane < 16) { sred[wave][n] = s_; ssred[wave][n] = ss_; }
    __syncthreads();
    if (tid < 16) {
        float sumv = 0.f, sumsq = 0.f;
#pragma unroll
        for (int wv = 0; wv < 4; ++wv) { sumv += sred[wv][tid]; sumsq += ssred[wv][tid]; }
        partials[((long long)blockIdx.x * 16 + tid) * 2 + 0] = sumv;
        partials[((long long)blockIdx.x * 16 + tid) * 2 + 1] = sumsq;
    }
}

// per-channel, per-half finalize. grid (COUT, 2).
template<int COUT>
__global__ void finalize2(const float* __restrict__ partials, int nblk_half, float invN,
                          const float* __restrict__ g, const float* __restrict__ be,
                          float* __restrict__ scale, float* __restrict__ shift)
{
    const int co = blockIdx.x;
    const int half = blockIdx.y;
    const float* P = partials + (size_t)half * nblk_half * COUT * 2;
    float s = 0.f, ss = 0.f;
    for (int i = threadIdx.x; i < nblk_half; i += NTHR) {
        s  += P[((long long)i * COUT + co) * 2 + 0];
        ss += P[((long long)i * COUT + co) * 2 + 1];
    }
    __shared__ float red[NTHR][2];
    red[threadIdx.x][0] = s; red[threadIdx.x][1] = ss;
    __syncthreads();
    for (int off = NTHR / 2; off > 0; off >>= 1) {
        if ((int)threadIdx.x < off) {
            red[threadIdx.x][0] += red[threadIdx.x + off][0];
            red[threadIdx.x][1] += red[threadIdx.x + off][1];
        }
        __syncthreads();
    }
    if (threadIdx.x == 0) {
        const float m = red[0][0] * invN;
        const float v = red[0][1] * invN - m * m;
        const float inv = rsqrtf(v + 1e-5f);
        const float sc = g[co] * inv;
        scale[half * COUT + co] = sc;
        shift[half * COUT + co] = be[co] - sc * m;
    }
}

// ---------------- weight prepacks (one launch) ------------------------------
template<int CIN, int KK, int DT, int NP, int S, int CT>
__device__ __forceinline__ void pack_one(int idx, const float* __restrict__ wgt,
                                         unsigned short* __restrict__ wp)
{
    const int j = idx & 7;
    const int l = (idx >> 3) & 63;
    int rest = idx >> 9;
    const int ct = rest % CT; rest /= CT;
    const int s = rest % S;
    const int p = rest / S;
    const int co = ct * 16 + (l & 15);
    const int k = (l >> 4) * 8 + j;
    int ci, t;
    if (DT == 2) { ci = k & (CIN - 1); t = p * 2 + (k >> 4); }
    else         { ci = s * 32 + k;    t = p; }
    float v = (t < KK) ? wgt[((long long)co * CIN + ci) * KK + t] : 0.f;
    wp[idx] = f2bf(v);
}

__global__ void build_all_wpacks(const float* __restrict__ w1, const float* __restrict__ w2,
                                 const float* __restrict__ w3,
                                 const float* __restrict__ tw1, const float* __restrict__ tw2,
                                 unsigned short* __restrict__ wp1,
                                 unsigned short* __restrict__ wp2, unsigned short* __restrict__ wp3,
                                 unsigned short* __restrict__ wpt1, unsigned short* __restrict__ wpt2)
{
    const int idx = blockIdx.x * NTHR + threadIdx.x;
    const int n1 = 512;
    const int n2 = 9 * 1 * 2 * 512;
    const int n3 = 17 * 1 * 4 * 512;
    const int nt1 = 5 * 2 * 4 * 512;
    const int nt2 = 3 * 2 * 4 * 512;
    if (idx < n1) {
        const int j = idx & 7, l = idx >> 3;
        const int co = l & 15, k = (l >> 4) * 8 + j;
        wp1[idx] = f2bf((k < 17) ? w1[co * 17 + k] : 0.f);
    }
    else if (idx < n1 + n2) pack_one<16, 17, 2, 9, 1, 2>(idx - n1, w2, wp2);
    else if (idx < n1 + n2 + n3) pack_one<32, 17, 1, 17, 1, 4>(idx - n1 - n2, w3, wp3);
    else if (idx < n1 + n2 + n3 + nt1) pack_one<64, 5, 1, 5, 2, 4>(idx - n1 - n2 - n3, tw1, wpt1);
    else if (idx < n1 + n2 + n3 + nt1 + nt2) pack_one<64, 3, 1, 3, 2, 4>(idx - n1 - n2 - n3 - nt1, tw2, wpt2);
}

// ---------------- MFMA conv, generalized (swapped operands) -----------------
// D[w][co]: co = ct*16 + (lane&15), w = w0 + wave*ST*16 + st*16 + kq*4 + e
// SRCM: 0 = src bf16 as-is; 1 = (max,min) pair + prev BN select + relu;
//       2 = raw y + prev BN + relu
// OUTM: 0 = store raw y; 1 = store pooled (max,min) of raw y
template<int CIN, int COUT, int KK, int PAD, int DT, int NP, int S, int CT, int ST,
         int SRCM, int OUTM>
__global__ __launch_bounds__(256)
void conv_mfma2(const unsigned short* __restrict__ xA, const unsigned short* __restrict__ xB,
                const float* __restrict__ pscale, const float* __restrict__ pshift,
                const unsigned short* __restrict__ wpack, const float* __restrict__ bias,
                unsigned short* __restrict__ outA, unsigned short* __restrict__ outB,
                float* __restrict__ partials, int W)
{
    constexpr int CHUNK = 4 * ST * 16;
    constexpr int ROWB = CIN * 2 + 16;
    constexpr int ROWS = CHUNK + KK + (DT - 1) + 1;
    constexpr int DPR = CIN / 2;
    __shared__ __align__(16) unsigned char lx[ROWS * ROWB];
    __shared__ float sred[4][CT][16];
    __shared__ float ssred[4][CT][16];
    __shared__ float scb[(SRCM > 0) ? CIN : 1];
    __shared__ float shb[(SRCM > 0) ? CIN : 1];

    const int tid = threadIdx.x;
    const int ntile = W / CHUNK;
    const int b = blockIdx.x / ntile;
    const int tile = blockIdx.x % ntile;
    const int w0 = tile * CHUNK;

    if (SRCM > 0) {
        if (tid < CIN) {
            scb[tid] = pscale[(b >> 8) * CIN + tid];
            shb[tid] = pshift[(b >> 8) * CIN + tid];
        }
        __syncthreads();
    }

    for (int d = tid; d < ROWS * DPR; d += 256) {
        const int row = d / DPR;
        const int col = d % DPR;
        const int gw = w0 - PAD + row;
        unsigned v = 0;
        if (gw >= 0 && gw < W) {
            const long long src = ((long long)b * W + gw) * CIN + col * 2;
            if (SRCM == 0) {
                v = *(const unsigned*)(xA + src);
            } else {
                const unsigned va = *(const unsigned*)(xA + src);
                const float sc0 = scb[col * 2], sh0 = shb[col * 2];
                const float sc1 = scb[col * 2 + 1], sh1 = shb[col * 2 + 1];
                float f0, f1;
                if (SRCM == 1) {
                    const unsigned vb = *(const unsigned*)(xB + src);
                    f0 = fmaxf(fmaf(sc0, (sc0 > 0.f) ? bflo(va) : bflo(vb), sh0), 0.f);
                    f1 = fmaxf(fmaf(sc1, (sc1 > 0.f) ? bfhi(va) : bfhi(vb), sh1), 0.f);
                } else {
                    f0 = fmaxf(fmaf(sc0, bflo(va), sh0), 0.f);
                    f1 = fmaxf(fmaf(sc1, bfhi(va), sh1), 0.f);
                }
                v = (unsigned)f2bf(f0) | ((unsigned)f2bf(f1) << 16);
            }
        }
        *(unsigned*)(lx + row * ROWB + col * 4) = v;
    }
    __syncthreads();

    const int lane = tid & 63, wave = tid >> 6;
    const int n = lane & 15, kq = lane >> 4;
    int rowbase, cbyte;
    if (DT == 2) { rowbase = wave * ST * 16 + n + (kq >> 1); cbyte = (kq & 1) * 16; }
    else         { rowbase = wave * ST * 16 + n;             cbyte = kq * 16; }

    f32x4 acc[ST][CT];
#pragma unroll
    for (int st = 0; st < ST; ++st)
#pragma unroll
        for (int ct = 0; ct < CT; ++ct) { acc[st][ct][0]=0.f; acc[st][ct][1]=0.f; acc[st][ct][2]=0.f; acc[st][ct][3]=0.f; }

#pragma unroll
    for (int p = 0; p < NP; ++p) {
#pragma unroll
        for (int s = 0; s < S; ++s) {
            bf16x8 a[CT];
#pragma unroll
            for (int ct = 0; ct < CT; ++ct)
                a[ct] = *(const bf16x8*)(wpack + (((long long)(p * S + s) * CT + ct) * 64 + lane) * 8);
#pragma unroll
            for (int st = 0; st < ST; ++st) {
                const int r = rowbase + st * 16 + p * DT;
                const bf16x8 bf = *(const bf16x8*)(lx + r * ROWB + cbyte + s * 64);
#pragma unroll
                for (int ct = 0; ct < CT; ++ct)
                    acc[st][ct] = __builtin_amdgcn_mfma_f32_16x16x32_bf16(bf, a[ct], acc[st][ct], 0, 0, 0);
            }
        }
    }

    // epilogue: D[w][co] -> pool over register axis; per-lane scalar stores
    float s_[CT], ss_[CT];
#pragma unroll
    for (int ct = 0; ct < CT; ++ct) { s_[ct] = 0.f; ss_[ct] = 0.f; }

#pragma unroll
    for (int st = 0; st < ST; ++st) {
        const int wbase = w0 + wave * ST * 16 + st * 16 + kq * 4;
#pragma unroll
        for (int ct = 0; ct < CT; ++ct) {
            const float bi = bias[ct * 16 + n];
            float v[4];
#pragma unroll
            for (int e = 0; e < 4; ++e) {
                v[e] = acc[st][ct][e] + bi;
                s_[ct] += v[e];
                ss_[ct] += v[e] * v[e];
            }
            if (OUTM == 0) {
#pragma unroll
                for (int e = 0; e < 4; ++e)
                    outA[((long long)b * W + wbase + e) * COUT + ct * 16 + n] = f2bf(v[e]);
            } else {
                const float mx = fmaxf(fmaxf(v[0], v[1]), fmaxf(v[2], v[3]));
                const float mn = fminf(fminf(v[0], v[1]), fminf(v[2], v[3]));
                const long long o = ((long long)b * (W >> 2) + (wbase >> 2)) * COUT + ct * 16 + n;
                outA[o] = f2bf(mx);
                outB[o] = f2bf(mn);
            }
        }
    }
#pragma unroll
    for (int ct = 0; ct < CT; ++ct) {
        s_[ct]  += __shfl_xor(s_[ct], 16, 64);  s_[ct]  += __shfl_xor(s_[ct], 32, 64);
        ss_[ct] += __shfl_xor(ss_[ct], 16, 64); ss_[ct] += __shfl_xor(ss_[ct], 32, 64);
    }
    if (lane < 16) {
#pragma unroll
        for (int ct = 0; ct < CT; ++ct) { sred[wave][ct][n] = s_[ct]; ssred[wave][ct][n] = ss_[ct]; }
    }
    __syncthreads();
    if (tid < COUT) {
        const int ct = tid >> 4, nn = tid & 15;
        float sumv = 0.f, sumsq = 0.f;
#pragma unroll
        for (int wv = 0; wv < 4; ++wv) { sumv += sred[wv][ct][nn]; sumsq += ssred[wv][ct][nn]; }
        partials[((long long)blockIdx.x * COUT + tid) * 2 + 0] = sumv;
        partials[((long long)blockIdx.x * COUT + tid) * 2 + 1] = sumsq;
    }
}

// ---------------- fused tail --------------------------------------------------
// blocks [0,512): BN+ReLU+adapool5 from raw y_t2, then IN-BLOCK flatnorm (ab)
//                 and knorm (kn).
// blocks [512,1024): h from stage3 minmax + BN select, center+norm -> Sv.
__global__ void tail_pool_srow(const unsigned short* __restrict__ yT2b,
                               const float* __restrict__ scT2, const float* __restrict__ shT2,
                               const unsigned short* __restrict__ yMax3,
                               const unsigned short* __restrict__ yMin3,
                               const float* __restrict__ scS3, const float* __restrict__ shS3,
                               float* __restrict__ kn, float* __restrict__ ab,
                               float* __restrict__ Sv)
{
    __shared__ float hb[128][64];
    const int tid = threadIdx.x;
    if (blockIdx.x < BSZ2) {
        const int b = blockIdx.x;
        __shared__ float pk[320];
        __shared__ float red2[NTHR];
        const uint2* yd = (const uint2*)(yT2b + (long long)b * 128 * 64);
        for (int i = tid; i < 128 * 16; i += 256) {
            const int w = i >> 4, c4 = (i & 15) * 4;
            const float* scp = scT2 + (b >> 8) * 64 + c4;
            const float* shp = shT2 + (b >> 8) * 64 + c4;
            const uint2 v = yd[i];
            hb[w][c4 + 0] = fmaxf(fmaf(scp[0], bflo(v.x), shp[0]), 0.f);
            hb[w][c4 + 1] = fmaxf(fmaf(scp[1], bfhi(v.x), shp[1]), 0.f);
            hb[w][c4 + 2] = fmaxf(fmaf(scp[2], bflo(v.y), shp[2]), 0.f);
            hb[w][c4 + 3] = fmaxf(fmaf(scp[3], bfhi(v.y), shp[3]), 0.f);
        }
        __syncthreads();
        const int bs[5] = {0, 25, 51, 76, 102};
        const int be5[5] = {26, 52, 77, 103, 128};
        for (int o = tid; o < 320; o += 256) {
            const int cc = o & 63, bin = o >> 6;
            float acc = 0.f;
            for (int w = bs[bin]; w < be5[bin]; ++w) acc += hb[w][cc];
            pk[cc * 5 + bin] = acc / (float)(be5[bin] - bs[bin]);
        }
        __syncthreads();
        float n2p = pk[tid] * pk[tid];
        if (tid < 64) n2p += pk[256 + tid] * pk[256 + tid];
        red2[tid] = n2p;
        __syncthreads();
        for (int off = NTHR / 2; off > 0; off >>= 1) {
            if (tid < off) red2[tid] += red2[tid + off];
            __syncthreads();
        }
        const float nrm = fmaxf(sqrtf(red2[0]), 1e-12f);
        for (int i = tid; i < 320; i += 256) ab[(long long)b * 320 + i] = pk[i] / nrm;
        if (tid < 64) {
            const float* p = pk + tid * 5;
            float m = 0.f;
            for (int t = 0; t < 5; ++t) m += p[t];
            m *= 0.2f;
            float v[5]; float q = 0.f;
            for (int t = 0; t < 5; ++t) { v[t] = p[t] - m; q += v[t] * v[t]; }
            const float n = fmaxf(sqrtf(q), 1e-12f);
            float* o = kn + ((long long)b * 64 + tid) * 5;
            for (int t = 0; t < 5; ++t) o[t] = v[t] / n;
        }
    } else {
        __shared__ float red[4][64];
        __shared__ float mrow[64];
        const int b = blockIdx.x - BSZ2;
        const int c = tid & 63, grp = tid >> 6;
        const uint2* ya = (const uint2*)(yMax3 + (long long)b * 128 * 64);
        const uint2* yb = (const uint2*)(yMin3 + (long long)b * 128 * 64);
        for (int i = tid; i < 128 * 16; i += 256) {
            const int w = i >> 4, c4 = (i & 15) * 4;
            const float* scp = scS3 + (b >> 8) * 64 + c4;
            const float* shp = shS3 + (b >> 8) * 64 + c4;
            const uint2 va = ya[i], vb = yb[i];
            hb[w][c4 + 0] = fmaxf(fmaf(scp[0], (scp[0] > 0.f) ? bflo(va.x) : bflo(vb.x), shp[0]), 0.f);
            hb[w][c4 + 1] = fmaxf(fmaf(scp[1], (scp[1] > 0.f) ? bfhi(va.x) : bfhi(vb.x), shp[1]), 0.f);
            hb[w][c4 + 2] = fmaxf(fmaf(scp[2], (scp[2] > 0.f) ? bflo(va.y) : bflo(vb.y), shp[2]), 0.f);
            hb[w][c4 + 3] = fmaxf(fmaf(scp[3], (scp[3] > 0.f) ? bfhi(va.y) : bfhi(vb.y), shp[3]), 0.f);
        }
        __syncthreads();
        float s = 0.f;
        for (int w = grp * 32; w < grp * 32 + 32; ++w) s += hb[w][c];
        red[grp][c] = s;
        __syncthreads();
        if (tid < 64) mrow[tid] = (red[0][tid] + red[1][tid] + red[2][tid] + red[3][tid]) / 128.f;
        __syncthreads();
        const float m = mrow[c];
        float q = 0.f;
        for (int w = grp * 32; w < grp * 32 + 32; ++w) { const float d = hb[w][c] - m; q += d * d; }
        red[grp][c] = q;
        __syncthreads();
        if (tid < 64) {
            const float n2 = red[0][tid] + red[1][tid] + red[2][tid] + red[3][tid];
            const float n = fmaxf(sqrtf(n2), 1e-12f);
            const float m0 = mrow[tid];
            const float h0 = (hb[0][tid] - m0) / n, h1 = (hb[1][tid] - m0) / n;
            const float hN1 = (hb[127][tid] - m0) / n, hN2 = (hb[126][tid] - m0) / n;
            float* o = Sv + ((long long)b * 64 + tid) * 5;
            o[0] = -(hN2 + hN1); o[1] = -hN1; o[2] = 0.f; o[3] = -h0; o[4] = -(h0 + h1);
        }
    }
}

// fused similarity + per-row log-softmax diag. grid (256, 3), block 256.
__global__ void simdot_nce(const float* __restrict__ kn, const float* __restrict__ Sv,
                           const float* __restrict__ ab, float* __restrict__ lp)
{
    const int j = threadIdx.x;
    const int i = blockIdx.x;
    const int z = blockIdx.y;
    const float* a;
    const float* b;
    float coef;
    if (z == 0)      { a = kn + (long long)i * 320;         b = Sv + (long long)(256 + j) * 320; coef = 10.f / 128.f; }
    else if (z == 1) { a = kn + (long long)(256 + i) * 320; b = Sv + (long long)j * 320;         coef = 10.f / 128.f; }
    else             { a = ab + (long long)i * 320;         b = ab + (long long)(256 + j) * 320; coef = 10.f; }
    const float4* a4 = (const float4*)a;
    const float4* b4 = (const float4*)b;
    float acc = 0.f;
#pragma unroll 8
    for (int d = 0; d < 80; ++d) {
        const float4 xv = a4[d], yv = b4[d];
        acc += xv.x * yv.x + xv.y * yv.y + xv.z * yv.z + xv.w * yv.w;
    }
    const float v = acc * coef;

    __shared__ float red[NTHR];
    __shared__ float sdiag;
    if (j == i) sdiag = v;
    red[j] = v;
    __syncthreads();
    for (int off = NTHR / 2; off > 0; off >>= 1) {
        if (j < off) red[j] = fmaxf(red[j], red[j + off]);
        __syncthreads();
    }
    const float mx = red[0];
    __syncthreads();
    red[j] = expf(v - mx);
    __syncthreads();
    for (int off = NTHR / 2; off > 0; off >>= 1) {
        if (j < off) red[j] += red[j + off];
        __syncthreads();
    }
    if (j == 0) lp[z * 256 + i] = sdiag - (mx + logf(red[0]));
}

// reduce lp -> final loss scalar
__global__ void final3(const float* __restrict__ lp, float* __restrict__ out)
{
    __shared__ float red[NTHR];
    const int tid = threadIdx.x;
    float l[3];
    for (int z = 0; z < 3; ++z) {
        red[tid] = lp[z * 256 + tid];
        __syncthreads();
        for (int off = NTHR / 2; off > 0; off >>= 1) {
            if (tid < off) red[tid] += red[tid + off];
            __syncthreads();
        }
        l[z] = red[0];
        __syncthreads();
    }
    if (tid == 0)
        out[0] = 0.5f * (-l[0] / 256.f - l[1] / 256.f) + 0.5f * (-l[2] / 256.f);
}

// ---------------------------------------------------------------------------

extern "C" void kernel_launch(void* const* d_in, const int* in_sizes, int n_in,
                              void* d_out, int out_size, void* d_ws, size_t ws_size,
                              hipStream_t stream)
{
    const float* x1  = (const float*)d_in[0];
    const float* x2  = (const float*)d_in[1];
    const float* w1  = (const float*)d_in[2];
    const float* b1  = (const float*)d_in[3];
    const float* g1  = (const float*)d_in[4];
    const float* be1 = (const float*)d_in[5];
    const float* w2  = (const float*)d_in[6];
    const float* b2  = (const float*)d_in[7];
    const float* g2  = (const float*)d_in[8];
    const float* be2 = (const float*)d_in[9];
    const float* w3  = (const float*)d_in[10];
    const float* b3  = (const float*)d_in[11];
    const float* g3  = (const float*)d_in[12];
    const float* be3 = (const float*)d_in[13];
    const float* tw1 = (const float*)d_in[14];
    const float* tb1 = (const float*)d_in[15];
    const float* tg1 = (const float*)d_in[16];
    const float* tbe1= (const float*)d_in[17];
    const float* tw2 = (const float*)d_in[18];
    const float* tb2 = (const float*)d_in[19];
    const float* tg2 = (const float*)d_in[20];
    const float* tbe2= (const float*)d_in[21];
    float* out = (float*)d_out;

    char* ws = (char*)d_ws;
    size_t off = 0;
    auto alloc = [&](size_t bytes) -> void* {
        off = (off + 255) & ~(size_t)255;
        void* p = ws + off;
        off += bytes;
        return p;
    };
    typedef unsigned short u16;
    u16* yMax1 = (u16*)alloc((size_t)BSZ2 * 2048 * 16 * 2);  // 33.6MB
    u16* yMin1 = (u16*)alloc((size_t)BSZ2 * 2048 * 16 * 2);  // 33.6MB
    u16* yMax2 = (u16*)alloc((size_t)BSZ2 * 512 * 32 * 2);   // 16.8MB
    u16* yMin2 = (u16*)alloc((size_t)BSZ2 * 512 * 32 * 2);   // 16.8MB
    u16* yMax3 = (u16*)alloc((size_t)BSZ2 * 128 * 64 * 2);   //  8.4MB
    u16* yMin3 = (u16*)alloc((size_t)BSZ2 * 128 * 64 * 2);   //  8.4MB
    u16* yT1   = (u16*)alloc((size_t)BSZ2 * 128 * 64 * 2);   //  8.4MB
    u16* yT2b  = (u16*)alloc((size_t)BSZ2 * 128 * 64 * 2);   //  8.4MB
    u16* wp1  = (u16*)alloc((size_t)512 * 2);
    u16* wp2  = (u16*)alloc((size_t)9 * 1 * 2 * 512 * 2);
    u16* wp3  = (u16*)alloc((size_t)17 * 1 * 4 * 512 * 2);
    u16* wpt1 = (u16*)alloc((size_t)5 * 2 * 4 * 512 * 2);
    u16* wpt2 = (u16*)alloc((size_t)3 * 2 * 4 * 512 * 2);
    float* kn   = (float*)alloc((size_t)BSZ2 * 320 * 4);
    float* ab   = (float*)alloc((size_t)BSZ2 * 320 * 4);
    float* Sv   = (float*)alloc((size_t)BSZ2 * 320 * 4);
    float* lp   = (float*)alloc((size_t)3 * 256 * 4);
    float* partials = (float*)alloc((size_t)16384 * 16 * 2 * 4);  // 2 MB
    float* scales = (float*)alloc((size_t)5 * 128 * 4);           // per-stage [2][C]
    float* shifts = (float*)alloc((size_t)5 * 128 * 4);
    float* sc1 = scales + 0 * 128, * sh1 = shifts + 0 * 128;
    float* sc2 = scales + 1 * 128, * sh2 = shifts + 1 * 128;
    float* sc3 = scales + 2 * 128, * sh3 = shifts + 2 * 128;
    float* sct1 = scales + 3 * 128, * sht1 = shifts + 3 * 128;
    float* sct2 = scales + 4 * 128, * sht2 = shifts + 4 * 128;

    build_all_wpacks<<<303, NTHR, 0, stream>>>(w1, w2, w3, tw1, tw2, wp1, wp2, wp3, wpt1, wpt2);

    // ---- stage 1: single conv pass (stats + pooled minmax) -> finalize ----
    {
        const int nblk = BSZ2 * (8192 / 512);    // WT=8 -> 8192 blocks
        conv1_mfma<8><<<nblk, 256, 0, stream>>>(x1, x2, wp1, b1, yMax1, yMin1, partials);
        dim3 fg(16, 2);
        finalize2<16><<<fg, NTHR, 0, stream>>>(partials, nblk / 2, 1.f / (256.f * 8192.f), g1, be1, sc1, sh1);
    }
    // ---- stage 2: stage-from-minmax(BN1) + conv + stats + pooled minmax ----
    {
        const int nblk = BSZ2 * (2048 / 512);
        conv_mfma2<16,32,17,8,2,9,1,2,8, 1,1><<<nblk, 256, 0, stream>>>(
            yMax1, yMin1, sc1, sh1, wp2, b2, yMax2, yMin2, partials, 2048);
        dim3 fg(32, 2);
        finalize2<32><<<fg, NTHR, 0, stream>>>(partials, nblk / 2, 1.f / (256.f * 2048.f), g2, be2, sc2, sh2);
    }
    // ---- stage 3: stage-from-minmax(BN2) + conv + stats + pooled minmax ----
    {
        const int nblk = BSZ2 * (512 / 256);
        conv_mfma2<32,64,17,8,1,17,1,4,4, 1,1><<<nblk, 256, 0, stream>>>(
            yMax2, yMin2, sc2, sh2, wp3, b3, yMax3, yMin3, partials, 512);
        dim3 fg(64, 2);
        finalize2<64><<<fg, NTHR, 0, stream>>>(partials, nblk / 2, 1.f / (256.f * 512.f), g3, be3, sc3, sh3);
    }
    // ---- template stage 1: stage-from-minmax(BN3) + conv + stats + y ----
    {
        conv_mfma2<64,64,5,2,1,5,2,4,2, 1,0><<<BSZ2, 256, 0, stream>>>(
            yMax3, yMin3, sc3, sh3, wpt1, tb1, yT1, nullptr, partials, 128);
        dim3 fg(64, 2);
        finalize2<64><<<fg, NTHR, 0, stream>>>(partials, 256, 1.f / (256.f * 128.f), tg1, tbe1, sct1, sht1);
    }
    // ---- template stage 2: stage-from-y(BNt1) + conv + stats + y ----
    {
        conv_mfma2<64,64,3,1,1,3,2,4,2, 2,0><<<BSZ2, 256, 0, stream>>>(
            yT1, nullptr, sct1, sht1, wpt2, tb2, yT2b, nullptr, partials, 128);
        dim3 fg(64, 2);
        finalize2<64><<<fg, NTHR, 0, stream>>>(partials, 256, 1.f / (256.f * 128.f), tg2, tbe2, sct2, sht2);
    }

    // ---- tail: adapool+norms (blocks 0..511) + srow (512..1023) ----
    tail_pool_srow<<<2 * BSZ2, 256, 0, stream>>>(yT2b, sct2, sht2, yMax3, yMin3, sc3, sh3, kn, ab, Sv);
    dim3 sg(256, 3);
    simdot_nce<<<sg, NTHR, 0, stream>>>(kn, Sv, ab, lp);
    final3<<<1, NTHR, 0, stream>>>(lp, out);
}

// Round 16
// 187.868 us; speedup vs baseline: 6.8396x; 1.0156x over previous
//
#include <hip/hip_runtime.h>
#include <hip/hip_bf16.h>
#include <math.h>

// ---------------------------------------------------------------------------
// TCCL model forward. Round 15 = R14 (191us) with stage-2 ST 8->4 (CHUNK 256):
// R14 post-mortem showed stage-2 latency-bound (occ 24%, MFMA 16%, VALU 31%,
// HBM 19%) -- 2048 blocks x 27KB LDS with a long serial staging phase.
// CHUNK=256 doubles block count, halves LDS (13KB -> ~12 blocks/CU) -> TLP
// hides the SRCM=1 staging latency.
// ---------------------------------------------------------------------------

#define BSZ2 512          // combined batch (x1 ++ x2)
#define NTHR 256

typedef __attribute__((ext_vector_type(8))) short bf16x8;
typedef __attribute__((ext_vector_type(4))) float f32x4;

static inline int ceil_divll(long long a, int b) { return (int)((a + b - 1) / b); }

__device__ __forceinline__ unsigned short f2bf(float f) {
    unsigned u = __float_as_uint(f);
    u = (u + 0x7FFFu + ((u >> 16) & 1u)) >> 16;
    return (unsigned short)u;
}
__device__ __forceinline__ float bflo(unsigned u) { return __uint_as_float(u << 16); }
__device__ __forceinline__ float bfhi(unsigned u) { return __uint_as_float(u & 0xFFFF0000u); }

// ---------------- stage 1 MFMA conv (Cin=1, K=17 padded to 32) --------------
// D[w][co], co = lane&15, w = kq*4+e. Single pass: stats partials + pooled
// (max,min) of raw y -> bf16 [b][2048][16] x2.
template<int WT>
__global__ __launch_bounds__(256)
void conv1_mfma(const float* __restrict__ x1, const float* __restrict__ x2,
                const unsigned short* __restrict__ wpack1, const float* __restrict__ bias,
                unsigned short* __restrict__ outMax, unsigned short* __restrict__ outMin,
                float* __restrict__ partials)
{
    constexpr int W = 8192;
    constexpr int CHUNK = 4 * WT * 16;
    __shared__ float xs[CHUNK + 32];
    __shared__ float sred[4][16];
    __shared__ float ssred[4][16];

    const int tid = threadIdx.x;
    const int ntile = W / CHUNK;
    const int b = blockIdx.x / ntile;
    const int w0 = (blockIdx.x % ntile) * CHUNK;
    const float* xrow = (b < 256) ? x1 + (long long)b * W : x2 + (long long)(b - 256) * W;

    for (int i = tid; i < CHUNK + 32; i += 256) {
        const int gw = w0 - 8 + i;
        xs[i] = (gw >= 0 && gw < W) ? xrow[gw] : 0.f;
    }
    __syncthreads();

    const int lane = tid & 63, wave = tid >> 6;
    const int n = lane & 15, kq = lane >> 4;
    const bf16x8 a = *(const bf16x8*)(wpack1 + lane * 8);   // weights: co=n, k=kq*8+j

    f32x4 acc[WT];
#pragma unroll
    for (int wt = 0; wt < WT; ++wt) { acc[wt][0]=0.f; acc[wt][1]=0.f; acc[wt][2]=0.f; acc[wt][3]=0.f; }

    const int base0 = wave * WT * 16 + n + kq * 8;          // x frag: row w=n, k=kq*8+j
#pragma unroll
    for (int wt = 0; wt < WT; ++wt) {
        bf16x8 bv;
#pragma unroll
        for (int j = 0; j < 8; ++j) {
            __hip_bfloat16 h = __float2bfloat16(xs[base0 + wt * 16 + j]);
            bv[j] = *reinterpret_cast<const short*>(&h);
        }
        acc[wt] = __builtin_amdgcn_mfma_f32_16x16x32_bf16(bv, a, acc[wt], 0, 0, 0);  // D[w][co]
    }

    const float bi = bias[n];
    float s_ = 0.f, ss_ = 0.f;
#pragma unroll
    for (int wt = 0; wt < WT; ++wt) {
        float v[4];
#pragma unroll
        for (int e = 0; e < 4; ++e) {
            v[e] = acc[wt][e] + bi;
            s_ += v[e]; ss_ += v[e] * v[e];
        }
        const float mx = fmaxf(fmaxf(v[0], v[1]), fmaxf(v[2], v[3]));
        const float mn = fminf(fminf(v[0], v[1]), fminf(v[2], v[3]));
        const int wp = (w0 >> 2) + wave * WT * 4 + wt * 4 + kq;
        outMax[((long long)b * 2048 + wp) * 16 + n] = f2bf(mx);
        outMin[((long long)b * 2048 + wp) * 16 + n] = f2bf(mn);
    }
    s_  += __shfl_xor(s_, 16, 64);  s_  += __shfl_xor(s_, 32, 64);
    ss_ += __shfl_xor(ss_, 16, 64); ss_ += __shfl_xor(ss_, 32, 64);
    if (lane < 16) { sred[wave][n] = s_; ssred[wave][n] = ss_; }
    __syncthreads();
    if (tid < 16) {
        float sumv = 0.f, sumsq = 0.f;
#pragma unroll
        for (int wv = 0; wv < 4; ++wv) { sumv += sred[wv][tid]; sumsq += ssred[wv][tid]; }
        partials[((long long)blockIdx.x * 16 + tid) * 2 + 0] = sumv;
        partials[((long long)blockIdx.x * 16 + tid) * 2 + 1] = sumsq;
    }
}

// per-channel, per-half finalize. grid (COUT, 2).
template<int COUT>
__global__ void finalize2(const float* __restrict__ partials, int nblk_half, float invN,
                          const float* __restrict__ g, const float* __restrict__ be,
                          float* __restrict__ scale, float* __restrict__ shift)
{
    const int co = blockIdx.x;
    const int half = blockIdx.y;
    const float* P = partials + (size_t)half * nblk_half * COUT * 2;
    float s = 0.f, ss = 0.f;
    for (int i = threadIdx.x; i < nblk_half; i += NTHR) {
        s  += P[((long long)i * COUT + co) * 2 + 0];
        ss += P[((long long)i * COUT + co) * 2 + 1];
    }
    __shared__ float red[NTHR][2];
    red[threadIdx.x][0] = s; red[threadIdx.x][1] = ss;
    __syncthreads();
    for (int off = NTHR / 2; off > 0; off >>= 1) {
        if ((int)threadIdx.x < off) {
            red[threadIdx.x][0] += red[threadIdx.x + off][0];
            red[threadIdx.x][1] += red[threadIdx.x + off][1];
        }
        __syncthreads();
    }
    if (threadIdx.x == 0) {
        const float m = red[0][0] * invN;
        const float v = red[0][1] * invN - m * m;
        const float inv = rsqrtf(v + 1e-5f);
        const float sc = g[co] * inv;
        scale[half * COUT + co] = sc;
        shift[half * COUT + co] = be[co] - sc * m;
    }
}

// ---------------- weight prepacks (one launch) ------------------------------
template<int CIN, int KK, int DT, int NP, int S, int CT>
__device__ __forceinline__ void pack_one(int idx, const float* __restrict__ wgt,
                                         unsigned short* __restrict__ wp)
{
    const int j = idx & 7;
    const int l = (idx >> 3) & 63;
    int rest = idx >> 9;
    const int ct = rest % CT; rest /= CT;
    const int s = rest % S;
    const int p = rest / S;
    const int co = ct * 16 + (l & 15);
    const int k = (l >> 4) * 8 + j;
    int ci, t;
    if (DT == 2) { ci = k & (CIN - 1); t = p * 2 + (k >> 4); }
    else         { ci = s * 32 + k;    t = p; }
    float v = (t < KK) ? wgt[((long long)co * CIN + ci) * KK + t] : 0.f;
    wp[idx] = f2bf(v);
}

__global__ void build_all_wpacks(const float* __restrict__ w1, const float* __restrict__ w2,
                                 const float* __restrict__ w3,
                                 const float* __restrict__ tw1, const float* __restrict__ tw2,
                                 unsigned short* __restrict__ wp1,
                                 unsigned short* __restrict__ wp2, unsigned short* __restrict__ wp3,
                                 unsigned short* __restrict__ wpt1, unsigned short* __restrict__ wpt2)
{
    const int idx = blockIdx.x * NTHR + threadIdx.x;
    const int n1 = 512;
    const int n2 = 9 * 1 * 2 * 512;
    const int n3 = 17 * 1 * 4 * 512;
    const int nt1 = 5 * 2 * 4 * 512;
    const int nt2 = 3 * 2 * 4 * 512;
    if (idx < n1) {
        const int j = idx & 7, l = idx >> 3;
        const int co = l & 15, k = (l >> 4) * 8 + j;
        wp1[idx] = f2bf((k < 17) ? w1[co * 17 + k] : 0.f);
    }
    else if (idx < n1 + n2) pack_one<16, 17, 2, 9, 1, 2>(idx - n1, w2, wp2);
    else if (idx < n1 + n2 + n3) pack_one<32, 17, 1, 17, 1, 4>(idx - n1 - n2, w3, wp3);
    else if (idx < n1 + n2 + n3 + nt1) pack_one<64, 5, 1, 5, 2, 4>(idx - n1 - n2 - n3, tw1, wpt1);
    else if (idx < n1 + n2 + n3 + nt1 + nt2) pack_one<64, 3, 1, 3, 2, 4>(idx - n1 - n2 - n3 - nt1, tw2, wpt2);
}

// ---------------- MFMA conv, generalized (swapped operands) -----------------
// D[w][co]: co = ct*16 + (lane&15), w = w0 + wave*ST*16 + st*16 + kq*4 + e
// SRCM: 0 = src bf16 as-is; 1 = (max,min) pair + prev BN select + relu;
//       2 = raw y + prev BN + relu
// OUTM: 0 = store raw y; 1 = store pooled (max,min) of raw y
template<int CIN, int COUT, int KK, int PAD, int DT, int NP, int S, int CT, int ST,
         int SRCM, int OUTM>
__global__ __launch_bounds__(256)
void conv_mfma2(const unsigned short* __restrict__ xA, const unsigned short* __restrict__ xB,
                const float* __restrict__ pscale, const float* __restrict__ pshift,
                const unsigned short* __restrict__ wpack, const float* __restrict__ bias,
                unsigned short* __restrict__ outA, unsigned short* __restrict__ outB,
                float* __restrict__ partials, int W)
{
    constexpr int CHUNK = 4 * ST * 16;
    constexpr int ROWB = CIN * 2 + 16;
    constexpr int ROWS = CHUNK + KK + (DT - 1) + 1;
    constexpr int DPR = CIN / 2;
    __shared__ __align__(16) unsigned char lx[ROWS * ROWB];
    __shared__ float sred[4][CT][16];
    __shared__ float ssred[4][CT][16];
    __shared__ float scb[(SRCM > 0) ? CIN : 1];
    __shared__ float shb[(SRCM > 0) ? CIN : 1];

    const int tid = threadIdx.x;
    const int ntile = W / CHUNK;
    const int b = blockIdx.x / ntile;
    const int tile = blockIdx.x % ntile;
    const int w0 = tile * CHUNK;

    if (SRCM > 0) {
        if (tid < CIN) {
            scb[tid] = pscale[(b >> 8) * CIN + tid];
            shb[tid] = pshift[(b >> 8) * CIN + tid];
        }
        __syncthreads();
    }

    for (int d = tid; d < ROWS * DPR; d += 256) {
        const int row = d / DPR;
        const int col = d % DPR;
        const int gw = w0 - PAD + row;
        unsigned v = 0;
        if (gw >= 0 && gw < W) {
            const long long src = ((long long)b * W + gw) * CIN + col * 2;
            if (SRCM == 0) {
                v = *(const unsigned*)(xA + src);
            } else {
                const unsigned va = *(const unsigned*)(xA + src);
                const float sc0 = scb[col * 2], sh0 = shb[col * 2];
                const float sc1 = scb[col * 2 + 1], sh1 = shb[col * 2 + 1];
                float f0, f1;
                if (SRCM == 1) {
                    const unsigned vb = *(const unsigned*)(xB + src);
                    f0 = fmaxf(fmaf(sc0, (sc0 > 0.f) ? bflo(va) : bflo(vb), sh0), 0.f);
                    f1 = fmaxf(fmaf(sc1, (sc1 > 0.f) ? bfhi(va) : bfhi(vb), sh1), 0.f);
                } else {
                    f0 = fmaxf(fmaf(sc0, bflo(va), sh0), 0.f);
                    f1 = fmaxf(fmaf(sc1, bfhi(va), sh1), 0.f);
                }
                v = (unsigned)f2bf(f0) | ((unsigned)f2bf(f1) << 16);
            }
        }
        *(unsigned*)(lx + row * ROWB + col * 4) = v;
    }
    __syncthreads();

    const int lane = tid & 63, wave = tid >> 6;
    const int n = lane & 15, kq = lane >> 4;
    int rowbase, cbyte;
    if (DT == 2) { rowbase = wave * ST * 16 + n + (kq >> 1); cbyte = (kq & 1) * 16; }
    else         { rowbase = wave * ST * 16 + n;             cbyte = kq * 16; }

    f32x4 acc[ST][CT];
#pragma unroll
    for (int st = 0; st < ST; ++st)
#pragma unroll
        for (int ct = 0; ct < CT; ++ct) { acc[st][ct][0]=0.f; acc[st][ct][1]=0.f; acc[st][ct][2]=0.f; acc[st][ct][3]=0.f; }

#pragma unroll
    for (int p = 0; p < NP; ++p) {
#pragma unroll
        for (int s = 0; s < S; ++s) {
            bf16x8 a[CT];
#pragma unroll
            for (int ct = 0; ct < CT; ++ct)
                a[ct] = *(const bf16x8*)(wpack + (((long long)(p * S + s) * CT + ct) * 64 + lane) * 8);
#pragma unroll
            for (int st = 0; st < ST; ++st) {
                const int r = rowbase + st * 16 + p * DT;
                const bf16x8 bf = *(const bf16x8*)(lx + r * ROWB + cbyte + s * 64);
#pragma unroll
                for (int ct = 0; ct < CT; ++ct)
                    acc[st][ct] = __builtin_amdgcn_mfma_f32_16x16x32_bf16(bf, a[ct], acc[st][ct], 0, 0, 0);
            }
        }
    }

    // epilogue: D[w][co] -> pool over register axis; per-lane scalar stores
    float s_[CT], ss_[CT];
#pragma unroll
    for (int ct = 0; ct < CT; ++ct) { s_[ct] = 0.f; ss_[ct] = 0.f; }

#pragma unroll
    for (int st = 0; st < ST; ++st) {
        const int wbase = w0 + wave * ST * 16 + st * 16 + kq * 4;
#pragma unroll
        for (int ct = 0; ct < CT; ++ct) {
            const float bi = bias[ct * 16 + n];
            float v[4];
#pragma unroll
            for (int e = 0; e < 4; ++e) {
                v[e] = acc[st][ct][e] + bi;
                s_[ct] += v[e];
                ss_[ct] += v[e] * v[e];
            }
            if (OUTM == 0) {
#pragma unroll
                for (int e = 0; e < 4; ++e)
                    outA[((long long)b * W + wbase + e) * COUT + ct * 16 + n] = f2bf(v[e]);
            } else {
                const float mx = fmaxf(fmaxf(v[0], v[1]), fmaxf(v[2], v[3]));
                const float mn = fminf(fminf(v[0], v[1]), fminf(v[2], v[3]));
                const long long o = ((long long)b * (W >> 2) + (wbase >> 2)) * COUT + ct * 16 + n;
                outA[o] = f2bf(mx);
                outB[o] = f2bf(mn);
            }
        }
    }
#pragma unroll
    for (int ct = 0; ct < CT; ++ct) {
        s_[ct]  += __shfl_xor(s_[ct], 16, 64);  s_[ct]  += __shfl_xor(s_[ct], 32, 64);
        ss_[ct] += __shfl_xor(ss_[ct], 16, 64); ss_[ct] += __shfl_xor(ss_[ct], 32, 64);
    }
    if (lane < 16) {
#pragma unroll
        for (int ct = 0; ct < CT; ++ct) { sred[wave][ct][n] = s_[ct]; ssred[wave][ct][n] = ss_[ct]; }
    }
    __syncthreads();
    if (tid < COUT) {
        const int ct = tid >> 4, nn = tid & 15;
        float sumv = 0.f, sumsq = 0.f;
#pragma unroll
        for (int wv = 0; wv < 4; ++wv) { sumv += sred[wv][ct][nn]; sumsq += ssred[wv][ct][nn]; }
        partials[((long long)blockIdx.x * COUT + tid) * 2 + 0] = sumv;
        partials[((long long)blockIdx.x * COUT + tid) * 2 + 1] = sumsq;
    }
}

// ---------------- fused tail --------------------------------------------------
// blocks [0,512): BN+ReLU+adapool5 from raw y_t2, then IN-BLOCK flatnorm (ab)
//                 and knorm (kn).
// blocks [512,1024): h from stage3 minmax + BN select, center+norm -> Sv.
__global__ void tail_pool_srow(const unsigned short* __restrict__ yT2b,
                               const float* __restrict__ scT2, const float* __restrict__ shT2,
                               const unsigned short* __restrict__ yMax3,
                               const unsigned short* __restrict__ yMin3,
                               const float* __restrict__ scS3, const float* __restrict__ shS3,
                               float* __restrict__ kn, float* __restrict__ ab,
                               float* __restrict__ Sv)
{
    __shared__ float hb[128][64];
    const int tid = threadIdx.x;
    if (blockIdx.x < BSZ2) {
        const int b = blockIdx.x;
        __shared__ float pk[320];
        __shared__ float red2[NTHR];
        const uint2* yd = (const uint2*)(yT2b + (long long)b * 128 * 64);
        for (int i = tid; i < 128 * 16; i += 256) {
            const int w = i >> 4, c4 = (i & 15) * 4;
            const float* scp = scT2 + (b >> 8) * 64 + c4;
            const float* shp = shT2 + (b >> 8) * 64 + c4;
            const uint2 v = yd[i];
            hb[w][c4 + 0] = fmaxf(fmaf(scp[0], bflo(v.x), shp[0]), 0.f);
            hb[w][c4 + 1] = fmaxf(fmaf(scp[1], bfhi(v.x), shp[1]), 0.f);
            hb[w][c4 + 2] = fmaxf(fmaf(scp[2], bflo(v.y), shp[2]), 0.f);
            hb[w][c4 + 3] = fmaxf(fmaf(scp[3], bfhi(v.y), shp[3]), 0.f);
        }
        __syncthreads();
        const int bs[5] = {0, 25, 51, 76, 102};
        const int be5[5] = {26, 52, 77, 103, 128};
        for (int o = tid; o < 320; o += 256) {
            const int cc = o & 63, bin = o >> 6;
            float acc = 0.f;
            for (int w = bs[bin]; w < be5[bin]; ++w) acc += hb[w][cc];
            pk[cc * 5 + bin] = acc / (float)(be5[bin] - bs[bin]);
        }
        __syncthreads();
        float n2p = pk[tid] * pk[tid];
        if (tid < 64) n2p += pk[256 + tid] * pk[256 + tid];
        red2[tid] = n2p;
        __syncthreads();
        for (int off = NTHR / 2; off > 0; off >>= 1) {
            if (tid < off) red2[tid] += red2[tid + off];
            __syncthreads();
        }
        const float nrm = fmaxf(sqrtf(red2[0]), 1e-12f);
        for (int i = tid; i < 320; i += 256) ab[(long long)b * 320 + i] = pk[i] / nrm;
        if (tid < 64) {
            const float* p = pk + tid * 5;
            float m = 0.f;
            for (int t = 0; t < 5; ++t) m += p[t];
            m *= 0.2f;
            float v[5]; float q = 0.f;
            for (int t = 0; t < 5; ++t) { v[t] = p[t] - m; q += v[t] * v[t]; }
            const float n = fmaxf(sqrtf(q), 1e-12f);
            float* o = kn + ((long long)b * 64 + tid) * 5;
            for (int t = 0; t < 5; ++t) o[t] = v[t] / n;
        }
    } else {
        __shared__ float red[4][64];
        __shared__ float mrow[64];
        const int b = blockIdx.x - BSZ2;
        const int c = tid & 63, grp = tid >> 6;
        const uint2* ya = (const uint2*)(yMax3 + (long long)b * 128 * 64);
        const uint2* yb = (const uint2*)(yMin3 + (long long)b * 128 * 64);
        for (int i = tid; i < 128 * 16; i += 256) {
            const int w = i >> 4, c4 = (i & 15) * 4;
            const float* scp = scS3 + (b >> 8) * 64 + c4;
            const float* shp = shS3 + (b >> 8) * 64 + c4;
            const uint2 va = ya[i], vb = yb[i];
            hb[w][c4 + 0] = fmaxf(fmaf(scp[0], (scp[0] > 0.f) ? bflo(va.x) : bflo(vb.x), shp[0]), 0.f);
            hb[w][c4 + 1] = fmaxf(fmaf(scp[1], (scp[1] > 0.f) ? bfhi(va.x) : bfhi(vb.x), shp[1]), 0.f);
            hb[w][c4 + 2] = fmaxf(fmaf(scp[2], (scp[2] > 0.f) ? bflo(va.y) : bflo(vb.y), shp[2]), 0.f);
            hb[w][c4 + 3] = fmaxf(fmaf(scp[3], (scp[3] > 0.f) ? bfhi(va.y) : bfhi(vb.y), shp[3]), 0.f);
        }
        __syncthreads();
        float s = 0.f;
        for (int w = grp * 32; w < grp * 32 + 32; ++w) s += hb[w][c];
        red[grp][c] = s;
        __syncthreads();
        if (tid < 64) mrow[tid] = (red[0][tid] + red[1][tid] + red[2][tid] + red[3][tid]) / 128.f;
        __syncthreads();
        const float m = mrow[c];
        float q = 0.f;
        for (int w = grp * 32; w < grp * 32 + 32; ++w) { const float d = hb[w][c] - m; q += d * d; }
        red[grp][c] = q;
        __syncthreads();
        if (tid < 64) {
            const float n2 = red[0][tid] + red[1][tid] + red[2][tid] + red[3][tid];
            const float n = fmaxf(sqrtf(n2), 1e-12f);
            const float m0 = mrow[tid];
            const float h0 = (hb[0][tid] - m0) / n, h1 = (hb[1][tid] - m0) / n;
            const float hN1 = (hb[127][tid] - m0) / n, hN2 = (hb[126][tid] - m0) / n;
            float* o = Sv + ((long long)b * 64 + tid) * 5;
            o[0] = -(hN2 + hN1); o[1] = -hN1; o[2] = 0.f; o[3] = -h0; o[4] = -(h0 + h1);
        }
    }
}

// fused similarity + per-row log-softmax diag. grid (256, 3), block 256.
__global__ void simdot_nce(const float* __restrict__ kn, const float* __restrict__ Sv,
                           const float* __restrict__ ab, float* __restrict__ lp)
{
    const int j = threadIdx.x;
    const int i = blockIdx.x;
    const int z = blockIdx.y;
    const float* a;
    const float* b;
    float coef;
    if (z == 0)      { a = kn + (long long)i * 320;         b = Sv + (long long)(256 + j) * 320; coef = 10.f / 128.f; }
    else if (z == 1) { a = kn + (long long)(256 + i) * 320; b = Sv + (long long)j * 320;         coef = 10.f / 128.f; }
    else             { a = ab + (long long)i * 320;         b = ab + (long long)(256 + j) * 320; coef = 10.f; }
    const float4* a4 = (const float4*)a;
    const float4* b4 = (const float4*)b;
    float acc = 0.f;
#pragma unroll 8
    for (int d = 0; d < 80; ++d) {
        const float4 xv = a4[d], yv = b4[d];
        acc += xv.x * yv.x + xv.y * yv.y + xv.z * yv.z + xv.w * yv.w;
    }
    const float v = acc * coef;

    __shared__ float red[NTHR];
    __shared__ float sdiag;
    if (j == i) sdiag = v;
    red[j] = v;
    __syncthreads();
    for (int off = NTHR / 2; off > 0; off >>= 1) {
        if (j < off) red[j] = fmaxf(red[j], red[j + off]);
        __syncthreads();
    }
    const float mx = red[0];
    __syncthreads();
    red[j] = expf(v - mx);
    __syncthreads();
    for (int off = NTHR / 2; off > 0; off >>= 1) {
        if (j < off) red[j] += red[j + off];
        __syncthreads();
    }
    if (j == 0) lp[z * 256 + i] = sdiag - (mx + logf(red[0]));
}

// reduce lp -> final loss scalar
__global__ void final3(const float* __restrict__ lp, float* __restrict__ out)
{
    __shared__ float red[NTHR];
    const int tid = threadIdx.x;
    float l[3];
    for (int z = 0; z < 3; ++z) {
        red[tid] = lp[z * 256 + tid];
        __syncthreads();
        for (int off = NTHR / 2; off > 0; off >>= 1) {
            if (tid < off) red[tid] += red[tid + off];
            __syncthreads();
        }
        l[z] = red[0];
        __syncthreads();
    }
    if (tid == 0)
        out[0] = 0.5f * (-l[0] / 256.f - l[1] / 256.f) + 0.5f * (-l[2] / 256.f);
}

// ---------------------------------------------------------------------------

extern "C" void kernel_launch(void* const* d_in, const int* in_sizes, int n_in,
                              void* d_out, int out_size, void* d_ws, size_t ws_size,
                              hipStream_t stream)
{
    const float* x1  = (const float*)d_in[0];
    const float* x2  = (const float*)d_in[1];
    const float* w1  = (const float*)d_in[2];
    const float* b1  = (const float*)d_in[3];
    const float* g1  = (const float*)d_in[4];
    const float* be1 = (const float*)d_in[5];
    const float* w2  = (const float*)d_in[6];
    const float* b2  = (const float*)d_in[7];
    const float* g2  = (const float*)d_in[8];
    const float* be2 = (const float*)d_in[9];
    const float* w3  = (const float*)d_in[10];
    const float* b3  = (const float*)d_in[11];
    const float* g3  = (const float*)d_in[12];
    const float* be3 = (const float*)d_in[13];
    const float* tw1 = (const float*)d_in[14];
    const float* tb1 = (const float*)d_in[15];
    const float* tg1 = (const float*)d_in[16];
    const float* tbe1= (const float*)d_in[17];
    const float* tw2 = (const float*)d_in[18];
    const float* tb2 = (const float*)d_in[19];
    const float* tg2 = (const float*)d_in[20];
    const float* tbe2= (const float*)d_in[21];
    float* out = (float*)d_out;

    char* ws = (char*)d_ws;
    size_t off = 0;
    auto alloc = [&](size_t bytes) -> void* {
        off = (off + 255) & ~(size_t)255;
        void* p = ws + off;
        off += bytes;
        return p;
    };
    typedef unsigned short u16;
    u16* yMax1 = (u16*)alloc((size_t)BSZ2 * 2048 * 16 * 2);  // 33.6MB
    u16* yMin1 = (u16*)alloc((size_t)BSZ2 * 2048 * 16 * 2);  // 33.6MB
    u16* yMax2 = (u16*)alloc((size_t)BSZ2 * 512 * 32 * 2);   // 16.8MB
    u16* yMin2 = (u16*)alloc((size_t)BSZ2 * 512 * 32 * 2);   // 16.8MB
    u16* yMax3 = (u16*)alloc((size_t)BSZ2 * 128 * 64 * 2);   //  8.4MB
    u16* yMin3 = (u16*)alloc((size_t)BSZ2 * 128 * 64 * 2);   //  8.4MB
    u16* yT1   = (u16*)alloc((size_t)BSZ2 * 128 * 64 * 2);   //  8.4MB
    u16* yT2b  = (u16*)alloc((size_t)BSZ2 * 128 * 64 * 2);   //  8.4MB
    u16* wp1  = (u16*)alloc((size_t)512 * 2);
    u16* wp2  = (u16*)alloc((size_t)9 * 1 * 2 * 512 * 2);
    u16* wp3  = (u16*)alloc((size_t)17 * 1 * 4 * 512 * 2);
    u16* wpt1 = (u16*)alloc((size_t)5 * 2 * 4 * 512 * 2);
    u16* wpt2 = (u16*)alloc((size_t)3 * 2 * 4 * 512 * 2);
    float* kn   = (float*)alloc((size_t)BSZ2 * 320 * 4);
    float* ab   = (float*)alloc((size_t)BSZ2 * 320 * 4);
    float* Sv   = (float*)alloc((size_t)BSZ2 * 320 * 4);
    float* lp   = (float*)alloc((size_t)3 * 256 * 4);
    float* partials = (float*)alloc((size_t)16384 * 16 * 2 * 4);  // 2 MB
    float* scales = (float*)alloc((size_t)5 * 128 * 4);           // per-stage [2][C]
    float* shifts = (float*)alloc((size_t)5 * 128 * 4);
    float* sc1 = scales + 0 * 128, * sh1 = shifts + 0 * 128;
    float* sc2 = scales + 1 * 128, * sh2 = shifts + 1 * 128;
    float* sc3 = scales + 2 * 128, * sh3 = shifts + 2 * 128;
    float* sct1 = scales + 3 * 128, * sht1 = shifts + 3 * 128;
    float* sct2 = scales + 4 * 128, * sht2 = shifts + 4 * 128;

    build_all_wpacks<<<303, NTHR, 0, stream>>>(w1, w2, w3, tw1, tw2, wp1, wp2, wp3, wpt1, wpt2);

    // ---- stage 1: single conv pass (stats + pooled minmax) -> finalize ----
    {
        const int nblk = BSZ2 * (8192 / 512);    // WT=8 -> 8192 blocks
        conv1_mfma<8><<<nblk, 256, 0, stream>>>(x1, x2, wp1, b1, yMax1, yMin1, partials);
        dim3 fg(16, 2);
        finalize2<16><<<fg, NTHR, 0, stream>>>(partials, nblk / 2, 1.f / (256.f * 8192.f), g1, be1, sc1, sh1);
    }
    // ---- stage 2: stage-from-minmax(BN1) + conv + stats + pooled minmax ----
    // CHUNK=256 (ST=4): 4096 blocks, 13KB LDS -> TLP hides SRCM staging latency
    {
        const int nblk = BSZ2 * (2048 / 256);
        conv_mfma2<16,32,17,8,2,9,1,2,4, 1,1><<<nblk, 256, 0, stream>>>(
            yMax1, yMin1, sc1, sh1, wp2, b2, yMax2, yMin2, partials, 2048);
        dim3 fg(32, 2);
        finalize2<32><<<fg, NTHR, 0, stream>>>(partials, nblk / 2, 1.f / (256.f * 2048.f), g2, be2, sc2, sh2);
    }
    // ---- stage 3: stage-from-minmax(BN2) + conv + stats + pooled minmax ----
    {
        const int nblk = BSZ2 * (512 / 256);
        conv_mfma2<32,64,17,8,1,17,1,4,4, 1,1><<<nblk, 256, 0, stream>>>(
            yMax2, yMin2, sc2, sh2, wp3, b3, yMax3, yMin3, partials, 512);
        dim3 fg(64, 2);
        finalize2<64><<<fg, NTHR, 0, stream>>>(partials, nblk / 2, 1.f / (256.f * 512.f), g3, be3, sc3, sh3);
    }
    // ---- template stage 1: stage-from-minmax(BN3) + conv + stats + y ----
    {
        conv_mfma2<64,64,5,2,1,5,2,4,2, 1,0><<<BSZ2, 256, 0, stream>>>(
            yMax3, yMin3, sc3, sh3, wpt1, tb1, yT1, nullptr, partials, 128);
        dim3 fg(64, 2);
        finalize2<64><<<fg, NTHR, 0, stream>>>(partials, 256, 1.f / (256.f * 128.f), tg1, tbe1, sct1, sht1);
    }
    // ---- template stage 2: stage-from-y(BNt1) + conv + stats + y ----
    {
        conv_mfma2<64,64,3,1,1,3,2,4,2, 2,0><<<BSZ2, 256, 0, stream>>>(
            yT1, nullptr, sct1, sht1, wpt2, tb2, yT2b, nullptr, partials, 128);
        dim3 fg(64, 2);
        finalize2<64><<<fg, NTHR, 0, stream>>>(partials, 256, 1.f / (256.f * 128.f), tg2, tbe2, sct2, sht2);
    }

    // ---- tail: adapool+norms (blocks 0..511) + srow (512..1023) ----
    tail_pool_srow<<<2 * BSZ2, 256, 0, stream>>>(yT2b, sct2, sht2, yMax3, yMin3, sc3, sh3, kn, ab, Sv);
    dim3 sg(256, 3);
    simdot_nce<<<sg, NTHR, 0, stream>>>(kn, Sv, ab, lp);
    final3<<<1, NTHR, 0, stream>>>(lp, out);
}

// Round 17
// 184.376 us; speedup vs baseline: 6.9692x; 1.0189x over previous
//
#include <hip/hip_runtime.h>
#include <hip/hip_bf16.h>
#include <math.h>

// ---------------------------------------------------------------------------
// TCCL model forward. Round 16 = R15 (188us) with stage-1/stage-2 FUSED:
//  - conv1 kernel is now stats-only (no y stores; -67MB write)
//  - conv12_fused: recomputes stage-1 conv from raw x via MFMA (BN1 known
//    after finalize1), BN1+ReLU+maxpool register-locally, writes pooled bf16
//    rows straight into the stage-2 LDS staging buffer (each (g,kq) owns one
//    row), then runs the verified stage-2 MFMA + minmax epilogue.
//    Replaces 70MB minmax read with 33.6MB x read. Net -100MB HBM traffic.
//  - yMax1/yMin1 buffers deleted. Everything else identical to R15.
// ---------------------------------------------------------------------------

#define BSZ2 512          // combined batch (x1 ++ x2)
#define NTHR 256

typedef __attribute__((ext_vector_type(8))) short bf16x8;
typedef __attribute__((ext_vector_type(4))) float f32x4;

static inline int ceil_divll(long long a, int b) { return (int)((a + b - 1) / b); }

__device__ __forceinline__ unsigned short f2bf(float f) {
    unsigned u = __float_as_uint(f);
    u = (u + 0x7FFFu + ((u >> 16) & 1u)) >> 16;
    return (unsigned short)u;
}
__device__ __forceinline__ float bflo(unsigned u) { return __uint_as_float(u << 16); }
__device__ __forceinline__ float bfhi(unsigned u) { return __uint_as_float(u & 0xFFFF0000u); }

// ---------------- stage 1 stats-only MFMA conv (Cin=1, K=17 pad 32) ---------
// D[w][co], co = lane&15, w = kq*4+e.
template<int WT>
__global__ __launch_bounds__(256)
void conv1_stats(const float* __restrict__ x1, const float* __restrict__ x2,
                 const unsigned short* __restrict__ wpack1, const float* __restrict__ bias,
                 float* __restrict__ partials)
{
    constexpr int W = 8192;
    constexpr int CHUNK = 4 * WT * 16;
    __shared__ float xs[CHUNK + 32];
    __shared__ float sred[4][16];
    __shared__ float ssred[4][16];

    const int tid = threadIdx.x;
    const int ntile = W / CHUNK;
    const int b = blockIdx.x / ntile;
    const int w0 = (blockIdx.x % ntile) * CHUNK;
    const float* xrow = (b < 256) ? x1 + (long long)b * W : x2 + (long long)(b - 256) * W;

    for (int i = tid; i < CHUNK + 32; i += 256) {
        const int gw = w0 - 8 + i;
        xs[i] = (gw >= 0 && gw < W) ? xrow[gw] : 0.f;
    }
    __syncthreads();

    const int lane = tid & 63, wave = tid >> 6;
    const int n = lane & 15, kq = lane >> 4;
    const bf16x8 a = *(const bf16x8*)(wpack1 + lane * 8);

    const float bi = bias[n];
    float s_ = 0.f, ss_ = 0.f;
    const int base0 = wave * WT * 16 + n + kq * 8;
#pragma unroll
    for (int wt = 0; wt < WT; ++wt) {
        bf16x8 bv;
#pragma unroll
        for (int j = 0; j < 8; ++j) {
            __hip_bfloat16 h = __float2bfloat16(xs[base0 + wt * 16 + j]);
            bv[j] = *reinterpret_cast<const short*>(&h);
        }
        f32x4 acc = {0.f, 0.f, 0.f, 0.f};
        acc = __builtin_amdgcn_mfma_f32_16x16x32_bf16(bv, a, acc, 0, 0, 0);
#pragma unroll
        for (int e = 0; e < 4; ++e) {
            const float y = acc[e] + bi;
            s_ += y; ss_ += y * y;
        }
    }
    s_  += __shfl_xor(s_, 16, 64);  s_  += __shfl_xor(s_, 32, 64);
    ss_ += __shfl_xor(ss_, 16, 64); ss_ += __shfl_xor(ss_, 32, 64);
    if (lane < 16) { sred[wave][n] = s_; ssred[wave][n] = ss_; }
    __syncthreads();
    if (tid < 16) {
        float sumv = 0.f, sumsq = 0.f;
#pragma unroll
        for (int wv = 0; wv < 4; ++wv) { sumv += sred[wv][tid]; sumsq += ssred[wv][tid]; }
        partials[((long long)blockIdx.x * 16 + tid) * 2 + 0] = sumv;
        partials[((long long)blockIdx.x * 16 + tid) * 2 + 1] = sumsq;
    }
}

// ---------------- fused stage1(recompute+BN1+pool) -> stage2 conv -----------
// grid = BSZ2 * 8 blocks (CHUNK=256 of stage-2 W=2048 domain).
__global__ __launch_bounds__(256)
void conv12_fused(const float* __restrict__ x1, const float* __restrict__ x2,
                  const unsigned short* __restrict__ wpack1, const float* __restrict__ b1v,
                  const float* __restrict__ sc1, const float* __restrict__ sh1,
                  const unsigned short* __restrict__ wp2, const float* __restrict__ b2v,
                  unsigned short* __restrict__ outMax, unsigned short* __restrict__ outMin,
                  float* __restrict__ partials)
{
    constexpr int W2 = 2048;
    constexpr int CHUNK = 256;          // ST=4
    constexpr int ST = 4, CT = 2, NP = 9, KK = 17;
    constexpr int CIN = 16, COUT = 32;
    constexpr int ROWB = CIN * 2 + 16;  // 48
    constexpr int ROWS = CHUNK + KK + 1 + 1;  // 275
    constexpr int XLEN = 1136;
    __shared__ float xs[XLEN];
    __shared__ __align__(16) unsigned char lx[ROWS * ROWB];
    __shared__ float sred[4][CT][16];
    __shared__ float ssred[4][CT][16];

    const int tid = threadIdx.x;
    const int b = blockIdx.x >> 3;
    const int tile = blockIdx.x & 7;
    const int w0 = tile * CHUNK;
    const int half = b >> 8;
    const float* xrow = (b < 256) ? x1 + (long long)b * 8192 : x2 + (long long)(b - 256) * 8192;
    const int xbase = 4 * w0 - 40;

    for (int i = tid; i < XLEN; i += 256) {
        const int gx = xbase + i;
        xs[i] = (gx >= 0 && gx < 8192) ? xrow[gx] : 0.f;
    }
    __syncthreads();

    const int lane = tid & 63, wave = tid >> 6;
    const int n = lane & 15, kq = lane >> 4;

    // ---- stage-1 recompute: 69 MFMA groups cover rows 0..274 of lx ----
    {
        const bf16x8 a1 = *(const bf16x8*)(wpack1 + lane * 8);
        const float bi1 = b1v[n];
        const float scv = sc1[half * 16 + n];
        const float shv = sh1[half * 16 + n];
        for (int i = 0; i < 18; ++i) {
            const int g = wave + 4 * i;
            if (g >= 69) break;
            bf16x8 bv;
#pragma unroll
            for (int j = 0; j < 8; ++j) {
                __hip_bfloat16 h = __float2bfloat16(xs[16 * g + n + kq * 8 + j]);
                bv[j] = *reinterpret_cast<const short*>(&h);
            }
            f32x4 acc = {0.f, 0.f, 0.f, 0.f};
            acc = __builtin_amdgcn_mfma_f32_16x16x32_bf16(bv, a1, acc, 0, 0, 0);  // D[w][co]
            const float t0 = fmaf(scv, acc[0] + bi1, shv);
            const float t1 = fmaf(scv, acc[1] + bi1, shv);
            const float t2 = fmaf(scv, acc[2] + bi1, shv);
            const float t3 = fmaf(scv, acc[3] + bi1, shv);
            const float pooled = fmaxf(fmaxf(fmaxf(t0, t1), fmaxf(t2, t3)), 0.f);
            const int row_local = 4 * g + kq;
            const int r_global = (w0 - 8) + row_local;
            if (row_local < ROWS) {
                const unsigned short val =
                    (r_global >= 0 && r_global < W2) ? f2bf(pooled) : (unsigned short)0;
                *(unsigned short*)(lx + row_local * ROWB + n * 2) = val;
            }
        }
    }
    __syncthreads();

    // ---- stage-2 MFMA (DT=2 path, identical to verified conv_mfma2) ----
    const int rowbase = wave * ST * 16 + n + (kq >> 1);
    const int cbyte = (kq & 1) * 16;

    f32x4 acc2[ST][CT];
#pragma unroll
    for (int st = 0; st < ST; ++st)
#pragma unroll
        for (int ct = 0; ct < CT; ++ct) { acc2[st][ct][0]=0.f; acc2[st][ct][1]=0.f; acc2[st][ct][2]=0.f; acc2[st][ct][3]=0.f; }

#pragma unroll
    for (int p = 0; p < NP; ++p) {
        bf16x8 a[CT];
#pragma unroll
        for (int ct = 0; ct < CT; ++ct)
            a[ct] = *(const bf16x8*)(wp2 + (((long long)p * CT + ct) * 64 + lane) * 8);
#pragma unroll
        for (int st = 0; st < ST; ++st) {
            const int r = rowbase + st * 16 + p * 2;
            const bf16x8 bf = *(const bf16x8*)(lx + r * ROWB + cbyte);
#pragma unroll
            for (int ct = 0; ct < CT; ++ct)
                acc2[st][ct] = __builtin_amdgcn_mfma_f32_16x16x32_bf16(bf, a[ct], acc2[st][ct], 0, 0, 0);
        }
    }

    // epilogue: stats + pooled minmax store (OUTM=1 path)
    float s_[CT], ss_[CT];
#pragma unroll
    for (int ct = 0; ct < CT; ++ct) { s_[ct] = 0.f; ss_[ct] = 0.f; }

#pragma unroll
    for (int st = 0; st < ST; ++st) {
        const int wbase = w0 + wave * ST * 16 + st * 16 + kq * 4;
#pragma unroll
        for (int ct = 0; ct < CT; ++ct) {
            const float bi = b2v[ct * 16 + n];
            float v[4];
#pragma unroll
            for (int e = 0; e < 4; ++e) {
                v[e] = acc2[st][ct][e] + bi;
                s_[ct] += v[e];
                ss_[ct] += v[e] * v[e];
            }
            const float mx = fmaxf(fmaxf(v[0], v[1]), fmaxf(v[2], v[3]));
            const float mn = fminf(fminf(v[0], v[1]), fminf(v[2], v[3]));
            const long long o = ((long long)b * (W2 >> 2) + (wbase >> 2)) * COUT + ct * 16 + n;
            outMax[o] = f2bf(mx);
            outMin[o] = f2bf(mn);
        }
    }
#pragma unroll
    for (int ct = 0; ct < CT; ++ct) {
        s_[ct]  += __shfl_xor(s_[ct], 16, 64);  s_[ct]  += __shfl_xor(s_[ct], 32, 64);
        ss_[ct] += __shfl_xor(ss_[ct], 16, 64); ss_[ct] += __shfl_xor(ss_[ct], 32, 64);
    }
    if (lane < 16) {
#pragma unroll
        for (int ct = 0; ct < CT; ++ct) { sred[wave][ct][n] = s_[ct]; ssred[wave][ct][n] = ss_[ct]; }
    }
    __syncthreads();
    if (tid < COUT) {
        const int ct = tid >> 4, nn = tid & 15;
        float sumv = 0.f, sumsq = 0.f;
#pragma unroll
        for (int wv = 0; wv < 4; ++wv) { sumv += sred[wv][ct][nn]; sumsq += ssred[wv][ct][nn]; }
        partials[((long long)blockIdx.x * COUT + tid) * 2 + 0] = sumv;
        partials[((long long)blockIdx.x * COUT + tid) * 2 + 1] = sumsq;
    }
}

// per-channel, per-half finalize. grid (COUT, 2).
template<int COUT>
__global__ void finalize2(const float* __restrict__ partials, int nblk_half, float invN,
                          const float* __restrict__ g, const float* __restrict__ be,
                          float* __restrict__ scale, float* __restrict__ shift)
{
    const int co = blockIdx.x;
    const int half = blockIdx.y;
    const float* P = partials + (size_t)half * nblk_half * COUT * 2;
    float s = 0.f, ss = 0.f;
    for (int i = threadIdx.x; i < nblk_half; i += NTHR) {
        s  += P[((long long)i * COUT + co) * 2 + 0];
        ss += P[((long long)i * COUT + co) * 2 + 1];
    }
    __shared__ float red[NTHR][2];
    red[threadIdx.x][0] = s; red[threadIdx.x][1] = ss;
    __syncthreads();
    for (int off = NTHR / 2; off > 0; off >>= 1) {
        if ((int)threadIdx.x < off) {
            red[threadIdx.x][0] += red[threadIdx.x + off][0];
            red[threadIdx.x][1] += red[threadIdx.x + off][1];
        }
        __syncthreads();
    }
    if (threadIdx.x == 0) {
        const float m = red[0][0] * invN;
        const float v = red[0][1] * invN - m * m;
        const float inv = rsqrtf(v + 1e-5f);
        const float sc = g[co] * inv;
        scale[half * COUT + co] = sc;
        shift[half * COUT + co] = be[co] - sc * m;
    }
}

// ---------------- weight prepacks (one launch) ------------------------------
template<int CIN, int KK, int DT, int NP, int S, int CT>
__device__ __forceinline__ void pack_one(int idx, const float* __restrict__ wgt,
                                         unsigned short* __restrict__ wp)
{
    const int j = idx & 7;
    const int l = (idx >> 3) & 63;
    int rest = idx >> 9;
    const int ct = rest % CT; rest /= CT;
    const int s = rest % S;
    const int p = rest / S;
    const int co = ct * 16 + (l & 15);
    const int k = (l >> 4) * 8 + j;
    int ci, t;
    if (DT == 2) { ci = k & (CIN - 1); t = p * 2 + (k >> 4); }
    else         { ci = s * 32 + k;    t = p; }
    float v = (t < KK) ? wgt[((long long)co * CIN + ci) * KK + t] : 0.f;
    wp[idx] = f2bf(v);
}

__global__ void build_all_wpacks(const float* __restrict__ w1, const float* __restrict__ w2,
                                 const float* __restrict__ w3,
                                 const float* __restrict__ tw1, const float* __restrict__ tw2,
                                 unsigned short* __restrict__ wp1,
                                 unsigned short* __restrict__ wp2, unsigned short* __restrict__ wp3,
                                 unsigned short* __restrict__ wpt1, unsigned short* __restrict__ wpt2)
{
    const int idx = blockIdx.x * NTHR + threadIdx.x;
    const int n1 = 512;
    const int n2 = 9 * 1 * 2 * 512;
    const int n3 = 17 * 1 * 4 * 512;
    const int nt1 = 5 * 2 * 4 * 512;
    const int nt2 = 3 * 2 * 4 * 512;
    if (idx < n1) {
        const int j = idx & 7, l = idx >> 3;
        const int co = l & 15, k = (l >> 4) * 8 + j;
        wp1[idx] = f2bf((k < 17) ? w1[co * 17 + k] : 0.f);
    }
    else if (idx < n1 + n2) pack_one<16, 17, 2, 9, 1, 2>(idx - n1, w2, wp2);
    else if (idx < n1 + n2 + n3) pack_one<32, 17, 1, 17, 1, 4>(idx - n1 - n2, w3, wp3);
    else if (idx < n1 + n2 + n3 + nt1) pack_one<64, 5, 1, 5, 2, 4>(idx - n1 - n2 - n3, tw1, wpt1);
    else if (idx < n1 + n2 + n3 + nt1 + nt2) pack_one<64, 3, 1, 3, 2, 4>(idx - n1 - n2 - n3 - nt1, tw2, wpt2);
}

// ---------------- MFMA conv, generalized (swapped operands) -----------------
// D[w][co]: co = ct*16 + (lane&15), w = w0 + wave*ST*16 + st*16 + kq*4 + e
// SRCM: 0 = src bf16 as-is; 1 = (max,min) pair + prev BN select + relu;
//       2 = raw y + prev BN + relu
// OUTM: 0 = store raw y; 1 = store pooled (max,min) of raw y
template<int CIN, int COUT, int KK, int PAD, int DT, int NP, int S, int CT, int ST,
         int SRCM, int OUTM>
__global__ __launch_bounds__(256)
void conv_mfma2(const unsigned short* __restrict__ xA, const unsigned short* __restrict__ xB,
                const float* __restrict__ pscale, const float* __restrict__ pshift,
                const unsigned short* __restrict__ wpack, const float* __restrict__ bias,
                unsigned short* __restrict__ outA, unsigned short* __restrict__ outB,
                float* __restrict__ partials, int W)
{
    constexpr int CHUNK = 4 * ST * 16;
    constexpr int ROWB = CIN * 2 + 16;
    constexpr int ROWS = CHUNK + KK + (DT - 1) + 1;
    constexpr int DPR = CIN / 2;
    __shared__ __align__(16) unsigned char lx[ROWS * ROWB];
    __shared__ float sred[4][CT][16];
    __shared__ float ssred[4][CT][16];
    __shared__ float scb[(SRCM > 0) ? CIN : 1];
    __shared__ float shb[(SRCM > 0) ? CIN : 1];

    const int tid = threadIdx.x;
    const int ntile = W / CHUNK;
    const int b = blockIdx.x / ntile;
    const int tile = blockIdx.x % ntile;
    const int w0 = tile * CHUNK;

    if (SRCM > 0) {
        if (tid < CIN) {
            scb[tid] = pscale[(b >> 8) * CIN + tid];
            shb[tid] = pshift[(b >> 8) * CIN + tid];
        }
        __syncthreads();
    }

    for (int d = tid; d < ROWS * DPR; d += 256) {
        const int row = d / DPR;
        const int col = d % DPR;
        const int gw = w0 - PAD + row;
        unsigned v = 0;
        if (gw >= 0 && gw < W) {
            const long long src = ((long long)b * W + gw) * CIN + col * 2;
            if (SRCM == 0) {
                v = *(const unsigned*)(xA + src);
            } else {
                const unsigned va = *(const unsigned*)(xA + src);
                const float sc0 = scb[col * 2], sh0 = shb[col * 2];
                const float sc1 = scb[col * 2 + 1], sh1 = shb[col * 2 + 1];
                float f0, f1;
                if (SRCM == 1) {
                    const unsigned vb = *(const unsigned*)(xB + src);
                    f0 = fmaxf(fmaf(sc0, (sc0 > 0.f) ? bflo(va) : bflo(vb), sh0), 0.f);
                    f1 = fmaxf(fmaf(sc1, (sc1 > 0.f) ? bfhi(va) : bfhi(vb), sh1), 0.f);
                } else {
                    f0 = fmaxf(fmaf(sc0, bflo(va), sh0), 0.f);
                    f1 = fmaxf(fmaf(sc1, bfhi(va), sh1), 0.f);
                }
                v = (unsigned)f2bf(f0) | ((unsigned)f2bf(f1) << 16);
            }
        }
        *(unsigned*)(lx + row * ROWB + col * 4) = v;
    }
    __syncthreads();

    const int lane = tid & 63, wave = tid >> 6;
    const int n = lane & 15, kq = lane >> 4;
    int rowbase, cbyte;
    if (DT == 2) { rowbase = wave * ST * 16 + n + (kq >> 1); cbyte = (kq & 1) * 16; }
    else         { rowbase = wave * ST * 16 + n;             cbyte = kq * 16; }

    f32x4 acc[ST][CT];
#pragma unroll
    for (int st = 0; st < ST; ++st)
#pragma unroll
        for (int ct = 0; ct < CT; ++ct) { acc[st][ct][0]=0.f; acc[st][ct][1]=0.f; acc[st][ct][2]=0.f; acc[st][ct][3]=0.f; }

#pragma unroll
    for (int p = 0; p < NP; ++p) {
#pragma unroll
        for (int s = 0; s < S; ++s) {
            bf16x8 a[CT];
#pragma unroll
            for (int ct = 0; ct < CT; ++ct)
                a[ct] = *(const bf16x8*)(wpack + (((long long)(p * S + s) * CT + ct) * 64 + lane) * 8);
#pragma unroll
            for (int st = 0; st < ST; ++st) {
                const int r = rowbase + st * 16 + p * DT;
                const bf16x8 bf = *(const bf16x8*)(lx + r * ROWB + cbyte + s * 64);
#pragma unroll
                for (int ct = 0; ct < CT; ++ct)
                    acc[st][ct] = __builtin_amdgcn_mfma_f32_16x16x32_bf16(bf, a[ct], acc[st][ct], 0, 0, 0);
            }
        }
    }

    float s_[CT], ss_[CT];
#pragma unroll
    for (int ct = 0; ct < CT; ++ct) { s_[ct] = 0.f; ss_[ct] = 0.f; }

#pragma unroll
    for (int st = 0; st < ST; ++st) {
        const int wbase = w0 + wave * ST * 16 + st * 16 + kq * 4;
#pragma unroll
        for (int ct = 0; ct < CT; ++ct) {
            const float bi = bias[ct * 16 + n];
            float v[4];
#pragma unroll
            for (int e = 0; e < 4; ++e) {
                v[e] = acc[st][ct][e] + bi;
                s_[ct] += v[e];
                ss_[ct] += v[e] * v[e];
            }
            if (OUTM == 0) {
#pragma unroll
                for (int e = 0; e < 4; ++e)
                    outA[((long long)b * W + wbase + e) * COUT + ct * 16 + n] = f2bf(v[e]);
            } else {
                const float mx = fmaxf(fmaxf(v[0], v[1]), fmaxf(v[2], v[3]));
                const float mn = fminf(fminf(v[0], v[1]), fminf(v[2], v[3]));
                const long long o = ((long long)b * (W >> 2) + (wbase >> 2)) * COUT + ct * 16 + n;
                outA[o] = f2bf(mx);
                outB[o] = f2bf(mn);
            }
        }
    }
#pragma unroll
    for (int ct = 0; ct < CT; ++ct) {
        s_[ct]  += __shfl_xor(s_[ct], 16, 64);  s_[ct]  += __shfl_xor(s_[ct], 32, 64);
        ss_[ct] += __shfl_xor(ss_[ct], 16, 64); ss_[ct] += __shfl_xor(ss_[ct], 32, 64);
    }
    if (lane < 16) {
#pragma unroll
        for (int ct = 0; ct < CT; ++ct) { sred[wave][ct][n] = s_[ct]; ssred[wave][ct][n] = ss_[ct]; }
    }
    __syncthreads();
    if (tid < COUT) {
        const int ct = tid >> 4, nn = tid & 15;
        float sumv = 0.f, sumsq = 0.f;
#pragma unroll
        for (int wv = 0; wv < 4; ++wv) { sumv += sred[wv][ct][nn]; sumsq += ssred[wv][ct][nn]; }
        partials[((long long)blockIdx.x * COUT + tid) * 2 + 0] = sumv;
        partials[((long long)blockIdx.x * COUT + tid) * 2 + 1] = sumsq;
    }
}

// ---------------- fused tail --------------------------------------------------
__global__ void tail_pool_srow(const unsigned short* __restrict__ yT2b,
                               const float* __restrict__ scT2, const float* __restrict__ shT2,
                               const unsigned short* __restrict__ yMax3,
                               const unsigned short* __restrict__ yMin3,
                               const float* __restrict__ scS3, const float* __restrict__ shS3,
                               float* __restrict__ kn, float* __restrict__ ab,
                               float* __restrict__ Sv)
{
    __shared__ float hb[128][64];
    const int tid = threadIdx.x;
    if (blockIdx.x < BSZ2) {
        const int b = blockIdx.x;
        __shared__ float pk[320];
        __shared__ float red2[NTHR];
        const uint2* yd = (const uint2*)(yT2b + (long long)b * 128 * 64);
        for (int i = tid; i < 128 * 16; i += 256) {
            const int w = i >> 4, c4 = (i & 15) * 4;
            const float* scp = scT2 + (b >> 8) * 64 + c4;
            const float* shp = shT2 + (b >> 8) * 64 + c4;
            const uint2 v = yd[i];
            hb[w][c4 + 0] = fmaxf(fmaf(scp[0], bflo(v.x), shp[0]), 0.f);
            hb[w][c4 + 1] = fmaxf(fmaf(scp[1], bfhi(v.x), shp[1]), 0.f);
            hb[w][c4 + 2] = fmaxf(fmaf(scp[2], bflo(v.y), shp[2]), 0.f);
            hb[w][c4 + 3] = fmaxf(fmaf(scp[3], bfhi(v.y), shp[3]), 0.f);
        }
        __syncthreads();
        const int bs[5] = {0, 25, 51, 76, 102};
        const int be5[5] = {26, 52, 77, 103, 128};
        for (int o = tid; o < 320; o += 256) {
            const int cc = o & 63, bin = o >> 6;
            float acc = 0.f;
            for (int w = bs[bin]; w < be5[bin]; ++w) acc += hb[w][cc];
            pk[cc * 5 + bin] = acc / (float)(be5[bin] - bs[bin]);
        }
        __syncthreads();
        float n2p = pk[tid] * pk[tid];
        if (tid < 64) n2p += pk[256 + tid] * pk[256 + tid];
        red2[tid] = n2p;
        __syncthreads();
        for (int off = NTHR / 2; off > 0; off >>= 1) {
            if (tid < off) red2[tid] += red2[tid + off];
            __syncthreads();
        }
        const float nrm = fmaxf(sqrtf(red2[0]), 1e-12f);
        for (int i = tid; i < 320; i += 256) ab[(long long)b * 320 + i] = pk[i] / nrm;
        if (tid < 64) {
            const float* p = pk + tid * 5;
            float m = 0.f;
            for (int t = 0; t < 5; ++t) m += p[t];
            m *= 0.2f;
            float v[5]; float q = 0.f;
            for (int t = 0; t < 5; ++t) { v[t] = p[t] - m; q += v[t] * v[t]; }
            const float n = fmaxf(sqrtf(q), 1e-12f);
            float* o = kn + ((long long)b * 64 + tid) * 5;
            for (int t = 0; t < 5; ++t) o[t] = v[t] / n;
        }
    } else {
        __shared__ float red[4][64];
        __shared__ float mrow[64];
        const int b = blockIdx.x - BSZ2;
        const int c = tid & 63, grp = tid >> 6;
        const uint2* ya = (const uint2*)(yMax3 + (long long)b * 128 * 64);
        const uint2* yb = (const uint2*)(yMin3 + (long long)b * 128 * 64);
        for (int i = tid; i < 128 * 16; i += 256) {
            const int w = i >> 4, c4 = (i & 15) * 4;
            const float* scp = scS3 + (b >> 8) * 64 + c4;
            const float* shp = shS3 + (b >> 8) * 64 + c4;
            const uint2 va = ya[i], vb = yb[i];
            hb[w][c4 + 0] = fmaxf(fmaf(scp[0], (scp[0] > 0.f) ? bflo(va.x) : bflo(vb.x), shp[0]), 0.f);
            hb[w][c4 + 1] = fmaxf(fmaf(scp[1], (scp[1] > 0.f) ? bfhi(va.x) : bfhi(vb.x), shp[1]), 0.f);
            hb[w][c4 + 2] = fmaxf(fmaf(scp[2], (scp[2] > 0.f) ? bflo(va.y) : bflo(vb.y), shp[2]), 0.f);
            hb[w][c4 + 3] = fmaxf(fmaf(scp[3], (scp[3] > 0.f) ? bfhi(va.y) : bfhi(vb.y), shp[3]), 0.f);
        }
        __syncthreads();
        float s = 0.f;
        for (int w = grp * 32; w < grp * 32 + 32; ++w) s += hb[w][c];
        red[grp][c] = s;
        __syncthreads();
        if (tid < 64) mrow[tid] = (red[0][tid] + red[1][tid] + red[2][tid] + red[3][tid]) / 128.f;
        __syncthreads();
        const float m = mrow[c];
        float q = 0.f;
        for (int w = grp * 32; w < grp * 32 + 32; ++w) { const float d = hb[w][c] - m; q += d * d; }
        red[grp][c] = q;
        __syncthreads();
        if (tid < 64) {
            const float n2 = red[0][tid] + red[1][tid] + red[2][tid] + red[3][tid];
            const float n = fmaxf(sqrtf(n2), 1e-12f);
            const float m0 = mrow[tid];
            const float h0 = (hb[0][tid] - m0) / n, h1 = (hb[1][tid] - m0) / n;
            const float hN1 = (hb[127][tid] - m0) / n, hN2 = (hb[126][tid] - m0) / n;
            float* o = Sv + ((long long)b * 64 + tid) * 5;
            o[0] = -(hN2 + hN1); o[1] = -hN1; o[2] = 0.f; o[3] = -h0; o[4] = -(h0 + h1);
        }
    }
}

// fused similarity + per-row log-softmax diag. grid (256, 3), block 256.
__global__ void simdot_nce(const float* __restrict__ kn, const float* __restrict__ Sv,
                           const float* __restrict__ ab, float* __restrict__ lp)
{
    const int j = threadIdx.x;
    const int i = blockIdx.x;
    const int z = blockIdx.y;
    const float* a;
    const float* b;
    float coef;
    if (z == 0)      { a = kn + (long long)i * 320;         b = Sv + (long long)(256 + j) * 320; coef = 10.f / 128.f; }
    else if (z == 1) { a = kn + (long long)(256 + i) * 320; b = Sv + (long long)j * 320;         coef = 10.f / 128.f; }
    else             { a = ab + (long long)i * 320;         b = ab + (long long)(256 + j) * 320; coef = 10.f; }
    const float4* a4 = (const float4*)a;
    const float4* b4 = (const float4*)b;
    float acc = 0.f;
#pragma unroll 8
    for (int d = 0; d < 80; ++d) {
        const float4 xv = a4[d], yv = b4[d];
        acc += xv.x * yv.x + xv.y * yv.y + xv.z * yv.z + xv.w * yv.w;
    }
    const float v = acc * coef;

    __shared__ float red[NTHR];
    __shared__ float sdiag;
    if (j == i) sdiag = v;
    red[j] = v;
    __syncthreads();
    for (int off = NTHR / 2; off > 0; off >>= 1) {
        if (j < off) red[j] = fmaxf(red[j], red[j + off]);
        __syncthreads();
    }
    const float mx = red[0];
    __syncthreads();
    red[j] = expf(v - mx);
    __syncthreads();
    for (int off = NTHR / 2; off > 0; off >>= 1) {
        if (j < off) red[j] += red[j + off];
        __syncthreads();
    }
    if (j == 0) lp[z * 256 + i] = sdiag - (mx + logf(red[0]));
}

// reduce lp -> final loss scalar
__global__ void final3(const float* __restrict__ lp, float* __restrict__ out)
{
    __shared__ float red[NTHR];
    const int tid = threadIdx.x;
    float l[3];
    for (int z = 0; z < 3; ++z) {
        red[tid] = lp[z * 256 + tid];
        __syncthreads();
        for (int off = NTHR / 2; off > 0; off >>= 1) {
            if (tid < off) red[tid] += red[tid + off];
            __syncthreads();
        }
        l[z] = red[0];
        __syncthreads();
    }
    if (tid == 0)
        out[0] = 0.5f * (-l[0] / 256.f - l[1] / 256.f) + 0.5f * (-l[2] / 256.f);
}

// ---------------------------------------------------------------------------

extern "C" void kernel_launch(void* const* d_in, const int* in_sizes, int n_in,
                              void* d_out, int out_size, void* d_ws, size_t ws_size,
                              hipStream_t stream)
{
    const float* x1  = (const float*)d_in[0];
    const float* x2  = (const float*)d_in[1];
    const float* w1  = (const float*)d_in[2];
    const float* b1  = (const float*)d_in[3];
    const float* g1  = (const float*)d_in[4];
    const float* be1 = (const float*)d_in[5];
    const float* w2  = (const float*)d_in[6];
    const float* b2  = (const float*)d_in[7];
    const float* g2  = (const float*)d_in[8];
    const float* be2 = (const float*)d_in[9];
    const float* w3  = (const float*)d_in[10];
    const float* b3  = (const float*)d_in[11];
    const float* g3  = (const float*)d_in[12];
    const float* be3 = (const float*)d_in[13];
    const float* tw1 = (const float*)d_in[14];
    const float* tb1 = (const float*)d_in[15];
    const float* tg1 = (const float*)d_in[16];
    const float* tbe1= (const float*)d_in[17];
    const float* tw2 = (const float*)d_in[18];
    const float* tb2 = (const float*)d_in[19];
    const float* tg2 = (const float*)d_in[20];
    const float* tbe2= (const float*)d_in[21];
    float* out = (float*)d_out;

    char* ws = (char*)d_ws;
    size_t off = 0;
    auto alloc = [&](size_t bytes) -> void* {
        off = (off + 255) & ~(size_t)255;
        void* p = ws + off;
        off += bytes;
        return p;
    };
    typedef unsigned short u16;
    u16* yMax2 = (u16*)alloc((size_t)BSZ2 * 512 * 32 * 2);   // 16.8MB
    u16* yMin2 = (u16*)alloc((size_t)BSZ2 * 512 * 32 * 2);   // 16.8MB
    u16* yMax3 = (u16*)alloc((size_t)BSZ2 * 128 * 64 * 2);   //  8.4MB
    u16* yMin3 = (u16*)alloc((size_t)BSZ2 * 128 * 64 * 2);   //  8.4MB
    u16* yT1   = (u16*)alloc((size_t)BSZ2 * 128 * 64 * 2);   //  8.4MB
    u16* yT2b  = (u16*)alloc((size_t)BSZ2 * 128 * 64 * 2);   //  8.4MB
    u16* wp1  = (u16*)alloc((size_t)512 * 2);
    u16* wp2  = (u16*)alloc((size_t)9 * 1 * 2 * 512 * 2);
    u16* wp3  = (u16*)alloc((size_t)17 * 1 * 4 * 512 * 2);
    u16* wpt1 = (u16*)alloc((size_t)5 * 2 * 4 * 512 * 2);
    u16* wpt2 = (u16*)alloc((size_t)3 * 2 * 4 * 512 * 2);
    float* kn   = (float*)alloc((size_t)BSZ2 * 320 * 4);
    float* ab   = (float*)alloc((size_t)BSZ2 * 320 * 4);
    float* Sv   = (float*)alloc((size_t)BSZ2 * 320 * 4);
    float* lp   = (float*)alloc((size_t)3 * 256 * 4);
    float* partials = (float*)alloc((size_t)16384 * 16 * 2 * 4);  // 2 MB
    float* scales = (float*)alloc((size_t)5 * 128 * 4);           // per-stage [2][C]
    float* shifts = (float*)alloc((size_t)5 * 128 * 4);
    float* sc1 = scales + 0 * 128, * sh1 = shifts + 0 * 128;
    float* sc2 = scales + 1 * 128, * sh2 = shifts + 1 * 128;
    float* sc3 = scales + 2 * 128, * sh3 = shifts + 2 * 128;
    float* sct1 = scales + 3 * 128, * sht1 = shifts + 3 * 128;
    float* sct2 = scales + 4 * 128, * sht2 = shifts + 4 * 128;

    build_all_wpacks<<<303, NTHR, 0, stream>>>(w1, w2, w3, tw1, tw2, wp1, wp2, wp3, wpt1, wpt2);

    // ---- stage 1: stats-only pass -> finalize ----
    {
        const int nblk = BSZ2 * (8192 / 512);    // WT=8 -> 8192 blocks
        conv1_stats<8><<<nblk, 256, 0, stream>>>(x1, x2, wp1, b1, partials);
        dim3 fg(16, 2);
        finalize2<16><<<fg, NTHR, 0, stream>>>(partials, nblk / 2, 1.f / (256.f * 8192.f), g1, be1, sc1, sh1);
    }
    // ---- fused stage1-recompute + stage2 conv + stats + pooled minmax ----
    {
        const int nblk = BSZ2 * 8;               // CHUNK=256 on W2=2048
        conv12_fused<<<nblk, 256, 0, stream>>>(x1, x2, wp1, b1, sc1, sh1,
                                               wp2, b2, yMax2, yMin2, partials);
        dim3 fg(32, 2);
        finalize2<32><<<fg, NTHR, 0, stream>>>(partials, nblk / 2, 1.f / (256.f * 2048.f), g2, be2, sc2, sh2);
    }
    // ---- stage 3: stage-from-minmax(BN2) + conv + stats + pooled minmax ----
    {
        const int nblk = BSZ2 * (512 / 256);
        conv_mfma2<32,64,17,8,1,17,1,4,4, 1,1><<<nblk, 256, 0, stream>>>(
            yMax2, yMin2, sc2, sh2, wp3, b3, yMax3, yMin3, partials, 512);
        dim3 fg(64, 2);
        finalize2<64><<<fg, NTHR, 0, stream>>>(partials, nblk / 2, 1.f / (256.f * 512.f), g3, be3, sc3, sh3);
    }
    // ---- template stage 1: stage-from-minmax(BN3) + conv + stats + y ----
    {
        conv_mfma2<64,64,5,2,1,5,2,4,2, 1,0><<<BSZ2, 256, 0, stream>>>(
            yMax3, yMin3, sc3, sh3, wpt1, tb1, yT1, nullptr, partials, 128);
        dim3 fg(64, 2);
        finalize2<64><<<fg, NTHR, 0, stream>>>(partials, 256, 1.f / (256.f * 128.f), tg1, tbe1, sct1, sht1);
    }
    // ---- template stage 2: stage-from-y(BNt1) + conv + stats + y ----
    {
        conv_mfma2<64,64,3,1,1,3,2,4,2, 2,0><<<BSZ2, 256, 0, stream>>>(
            yT1, nullptr, sct1, sht1, wpt2, tb2, yT2b, nullptr, partials, 128);
        dim3 fg(64, 2);
        finalize2<64><<<fg, NTHR, 0, stream>>>(partials, 256, 1.f / (256.f * 128.f), tg2, tbe2, sct2, sht2);
    }

    // ---- tail: adapool+norms (blocks 0..511) + srow (512..1023) ----
    tail_pool_srow<<<2 * BSZ2, 256, 0, stream>>>(yT2b, sct2, sht2, yMax3, yMin3, sc3, sh3, kn, ab, Sv);
    dim3 sg(256, 3);
    simdot_nce<<<sg, NTHR, 0, stream>>>(kn, Sv, ab, lp);
    final3<<<1, NTHR, 0, stream>>>(lp, out);
}